// Round 9
// baseline (260.011 us; speedup 1.0000x reference)
//
#include <hip/hip_runtime.h>
#include <hip/hip_bf16.h>

typedef float f32x4 __attribute__((ext_vector_type(4)));
typedef unsigned int u32x4 __attribute__((ext_vector_type(4)));
typedef __bf16 bf16x8 __attribute__((ext_vector_type(8)));

#define NSP 4096
#define KTOT 2304

static __device__ __forceinline__ float bflo(unsigned u) {
  return __builtin_bit_cast(float, u << 16);
}
static __device__ __forceinline__ float bfhi(unsigned u) {
  return __builtin_bit_cast(float, u & 0xffff0000u);
}
static __device__ __forceinline__ unsigned short bfbits(float f) {
  return __builtin_bit_cast(unsigned short, (__bf16)f);
}
static __device__ __forceinline__ unsigned packbf2(float f0, float f1) {
  return (unsigned)bfbits(f0) | ((unsigned)bfbits(f1) << 16);
}
static __device__ __forceinline__ float bf16f(unsigned short h) {
  return __builtin_bit_cast(float, (unsigned)h << 16);
}

// ---------- x (B,C,H,W) f32 -> XH (B,H,W,C) bf16 hi + XL bf16 residual ----------
__global__ __launch_bounds__(256) void k_nhwc(const float* __restrict__ x,
                                              unsigned short* __restrict__ XH,
                                              unsigned short* __restrict__ XL) {
  const int by = blockIdx.x;            // b*64 + y
  const int t = threadIdx.x;
  const int xw = t & 63;
  const int cq = t >> 6;                // 0..3
  const float* xp = x + (((by >> 6) * 256 * 64 + (by & 63)) * 64 + xw);
  unsigned short* oh = XH + (by * 64 + xw) * 256;
  unsigned short* ol = XL + (by * 64 + xw) * 256;
#pragma unroll
  for (int j8 = 0; j8 < 8; ++j8) {
    const int c0 = cq * 64 + j8 * 8;
    u32x4 vh, vl;
#pragma unroll
    for (int d = 0; d < 4; ++d) {
      float f0 = xp[(c0 + 2 * d) * 4096];
      float f1 = xp[(c0 + 2 * d + 1) * 4096];
      unsigned short h0 = bfbits(f0), h1 = bfbits(f1);
      float r0 = f0 - bf16f(h0);
      float r1 = f1 - bf16f(h1);
      vh[d] = (unsigned)h0 | ((unsigned)h1 << 16);
      vl[d] = packbf2(r0, r1);
    }
    *(u32x4*)(oh + c0) = vh;
    *(u32x4*)(ol + c0) = vl;
  }
}

// ---------- w_conv (Co,C,3,3) f32 -> AW (Co, k*256+c) bf16 ----------
__global__ void k_wprep(const float* __restrict__ wc, unsigned short* __restrict__ AW) {
  int idx = blockIdx.x * 256 + threadIdx.x;
  if (idx >= 256 * KTOT) return;
  int o = idx / KTOT;
  int r = idx - o * KTOT;
  int k = r >> 8, c = r & 255;
  AW[idx] = bfbits(wc[(o * 256 + c) * 9 + k]);
}

// ---------- w_offset (27,256,3,3) f32 -> AOH/AOL [32][tap*256+c] bf16 hi/lo ----------
__global__ void k_wprep_off(const float* __restrict__ wof,
                            unsigned short* __restrict__ AOH,
                            unsigned short* __restrict__ AOL) {
  int idx = blockIdx.x * 256 + threadIdx.x;   // 32*2304 = 73728
  if (idx >= 32 * KTOT) return;
  int m = idx / KTOT;
  int r = idx - m * KTOT;
  int t = r >> 8, c = r & 255;
  float v = (m < 27) ? wof[(m * 256 + c) * 9 + t] : 0.f;
  unsigned short h = bfbits(v);
  AOH[idx] = h;
  AOL[idx] = bfbits(v - bf16f(h));
}

// ---------- offset conv via split-bf16 MFMA: raw PY/PX/MS logits ----------
__global__ __launch_bounds__(256) void k_offc_mfma(const unsigned short* __restrict__ AOH,
                                                   const unsigned short* __restrict__ AOL,
                                                   const unsigned short* __restrict__ XH,
                                                   const unsigned short* __restrict__ XL,
                                                   float* __restrict__ PY,
                                                   float* __restrict__ PX,
                                                   float* __restrict__ MS) {
  const int tid = threadIdx.x;
  const int l = tid & 63;
  const int w = tid >> 6;                 // 4 waves, each owns 16 cols
  const int bid = blockIdx.x;
  const int b = bid & 7;                  // XCD swizzle: one batch per XCD
  const int y = bid >> 3;
  const int xcol = w * 16 + (l & 15);
  const int kq = (l >> 4) * 8;            // k sub-offset (elements)
  const unsigned short* xb = XH + b * (64 * 64 * 256);
  const unsigned short* xlb = XL + b * (64 * 64 * 256);
  const int mr = l & 15;

  f32x4 acc0 = (f32x4){0.f, 0.f, 0.f, 0.f};
  f32x4 acc1 = (f32x4){0.f, 0.f, 0.f, 0.f};

#pragma unroll
  for (int tap = 0; tap < 9; ++tap) {
    const int yy = y + tap / 3 - 1;
    const int xx = xcol + tap % 3 - 1;
    const bool valid = ((unsigned)yy < 64u) & ((unsigned)xx < 64u);
    const unsigned short* bp = xb + (yy * 64 + xx) * 256 + kq;
    const unsigned short* blp = xlb + (yy * 64 + xx) * 256 + kq;
    const unsigned short* a0 = AOH + mr * KTOT + tap * 256 + kq;
    const unsigned short* a1 = AOH + (mr + 16) * KTOT + tap * 256 + kq;
    const unsigned short* c0p = AOL + mr * KTOT + tap * 256 + kq;
    const unsigned short* c1p = AOL + (mr + 16) * KTOT + tap * 256 + kq;
#pragma unroll
    for (int kc = 0; kc < 8; ++kc) {
      u32x4 zh = (u32x4){0u, 0u, 0u, 0u};
      u32x4 bhu = valid ? *(const u32x4*)(bp + kc * 32) : zh;
      u32x4 blu = valid ? *(const u32x4*)(blp + kc * 32) : zh;
      bf16x8 bh = __builtin_bit_cast(bf16x8, bhu);
      bf16x8 bl = __builtin_bit_cast(bf16x8, blu);
      bf16x8 ah0 = *(const bf16x8*)(a0 + kc * 32);
      bf16x8 ah1 = *(const bf16x8*)(a1 + kc * 32);
      bf16x8 al0 = *(const bf16x8*)(c0p + kc * 32);
      bf16x8 al1 = *(const bf16x8*)(c1p + kc * 32);
      acc0 = __builtin_amdgcn_mfma_f32_16x16x32_bf16(ah0, bh, acc0, 0, 0, 0);
      acc1 = __builtin_amdgcn_mfma_f32_16x16x32_bf16(ah1, bh, acc1, 0, 0, 0);
      acc0 = __builtin_amdgcn_mfma_f32_16x16x32_bf16(ah0, bl, acc0, 0, 0, 0);
      acc1 = __builtin_amdgcn_mfma_f32_16x16x32_bf16(ah1, bl, acc1, 0, 0, 0);
      acc0 = __builtin_amdgcn_mfma_f32_16x16x32_bf16(al0, bh, acc0, 0, 0, 0);
      acc1 = __builtin_amdgcn_mfma_f32_16x16x32_bf16(al1, bh, acc1, 0, 0, 0);
    }
  }

  // D layout: col=lane&15 (=our n), row=(lane>>4)*4+reg
  const int s = y * 64 + xcol;
#pragma unroll
  for (int mf = 0; mf < 2; ++mf) {
    f32x4 a = mf ? acc1 : acc0;
#pragma unroll
    for (int r = 0; r < 4; ++r) {
      int m = mf * 16 + (l >> 4) * 4 + r;
      if (m < 27) {
        int which = m / 9;
        int mm = m - which * 9;
        float* dst = which == 0 ? PY : (which == 1 ? PX : MS);
        dst[((b * 9 + mm) << 12) + s] = a[r];
      }
    }
  }
}

// ---------- precompute bilinear metadata: weights (masked) + packed corner idx ----------
__global__ void k_xform3(const float* __restrict__ PY, const float* __restrict__ PX,
                         const float* __restrict__ MS, f32x4* __restrict__ W4,
                         unsigned* __restrict__ C4) {
  int idx = blockIdx.x * 256 + threadIdx.x;   // (b*9+k)*4096 + s
  if (idx >= 8 * 9 * NSP) return;
  int s = idx & 4095;
  int k = (idx >> 12) % 9;
  float py = PY[idx] + (float)(s >> 6) - 1.f + (float)(k / 3);
  float px = PX[idx] + (float)(s & 63) - 1.f + (float)(k % 3);
  float mk = 1.f / (1.f + __expf(-MS[idx]));

  float y0f = floorf(py), x0f = floorf(px);
  float ly = py - y0f, lx = px - x0f;
  int y0 = (int)y0f, x0 = (int)x0f;
  int y1 = y0 + 1, x1 = x0 + 1;
  float omy = 1.f - ly, omx = 1.f - lx;
  bool y0v = (unsigned)y0 < 64u, y1v = (unsigned)y1 < 64u;
  bool x0v = (unsigned)x0 < 64u, x1v = (unsigned)x1 < 64u;
  f32x4 wv;
  wv[0] = (y0v && x0v) ? omy * omx * mk : 0.f;
  wv[1] = (y0v && x1v) ? omy * lx * mk : 0.f;
  wv[2] = (y1v && x0v) ? ly * omx * mk : 0.f;
  wv[3] = (y1v && x1v) ? ly * lx * mk : 0.f;
  int y0c = min(max(y0, 0), 63), y1c = min(max(y1, 0), 63);
  int x0c = min(max(x0, 0), 63), x1c = min(max(x1, 0), 63);
  unsigned p00 = (unsigned)(y0c * 64 + x0c);
  unsigned p11 = (unsigned)(y1c * 64 + x1c);
  W4[idx] = wv;
  C4[idx] = p00 | (p11 << 16);
}

// ---------- fused sampling + implicit GEMM (128x128 tile, dbuf, 2 blocks/CU) ----------
struct Bld16 {
  u32x4 g00a, g00b, g01a, g01b, g10a, g10b, g11a, g11b;
  f32x4 wv;
};

static __device__ __forceinline__ void loadB16(const unsigned short* __restrict__ xb,
                                               const f32x4* __restrict__ W4,
                                               const unsigned* __restrict__ C4,
                                               int b, int k, int c0, int bc, int s,
                                               Bld16& r) {
  int ci = (b * 9 + k) * NSP + s;
  r.wv = W4[ci];
  unsigned c4 = C4[ci];
  unsigned p00 = c4 & 0xffffu, p11 = c4 >> 16;
  unsigned p01 = (p00 & ~63u) | (p11 & 63u);
  unsigned p10 = (p11 & ~63u) | (p00 & 63u);
  const unsigned short* base = xb + (c0 + bc);
  const unsigned short* q00 = base + (p00 << 8);
  const unsigned short* q01 = base + (p01 << 8);
  const unsigned short* q10 = base + (p10 << 8);
  const unsigned short* q11 = base + (p11 << 8);
  r.g00a = *(const u32x4*)q00;
  r.g00b = *(const u32x4*)(q00 + 8);
  r.g01a = *(const u32x4*)q01;
  r.g01b = *(const u32x4*)(q01 + 8);
  r.g10a = *(const u32x4*)q10;
  r.g10b = *(const u32x4*)(q10 + 8);
  r.g11a = *(const u32x4*)q11;
  r.g11b = *(const u32x4*)(q11 + 8);
}

static __device__ __forceinline__ void blendB16(const Bld16& r, u32x4& o0, u32x4& o1) {
#pragma unroll
  for (int d = 0; d < 4; ++d) {
    float a0 = r.wv[0] * bflo(r.g00a[d]) + r.wv[1] * bflo(r.g01a[d]) +
               r.wv[2] * bflo(r.g10a[d]) + r.wv[3] * bflo(r.g11a[d]);
    float a1 = r.wv[0] * bfhi(r.g00a[d]) + r.wv[1] * bfhi(r.g01a[d]) +
               r.wv[2] * bfhi(r.g10a[d]) + r.wv[3] * bfhi(r.g11a[d]);
    o0[d] = packbf2(a0, a1);
    float b0 = r.wv[0] * bflo(r.g00b[d]) + r.wv[1] * bflo(r.g01b[d]) +
               r.wv[2] * bflo(r.g10b[d]) + r.wv[3] * bflo(r.g11b[d]);
    float b1 = r.wv[0] * bfhi(r.g00b[d]) + r.wv[1] * bfhi(r.g01b[d]) +
               r.wv[2] * bfhi(r.g10b[d]) + r.wv[3] * bfhi(r.g11b[d]);
    o1[d] = packbf2(b0, b1);
  }
}

__global__ __launch_bounds__(512) void k_gemm(const unsigned short* __restrict__ AW,
                                              const unsigned short* __restrict__ XH,
                                              const f32x4* __restrict__ W4,
                                              const unsigned* __restrict__ C4,
                                              float* __restrict__ out) {
  // double buffer: per buffer 32 KB = A [128][64 bf16] (16 KB) + B [128][64 bf16] (16 KB)
  __shared__ u32x4 lds2[2][2048];
  unsigned char* ldsbase = (unsigned char*)lds2;

  const int tid = threadIdx.x;
  const int bid = blockIdx.x;
  const int b = bid & 7;              // XCD swizzle: one batch per XCD
  const int s0 = ((bid >> 3) & 31) * 128;
  const int mh = bid >> 8;            // M-half: rows mh*128 .. +128

  const int l = tid & 63;
  const int w = tid >> 6;             // 8 waves = 4 spatial (2M x 2N) x 2 kk
  const int sw = w & 3;
  const int kk = w >> 2;
  const int wm = (sw >> 1) * 64;
  const int wn = (sw & 1) * 64;

  // A staging: row am (0..127), quarter ah (0..3) -> 2 x u32x4 (32B)
  const int am = tid & 127;
  const int ah = tid >> 7;
  const unsigned short* arow = AW + (mh * 128 + am) * KTOT + ah * 16;
  const unsigned swa = (unsigned)(am & 7) << 4;

  // B staging: pixel bn (0..127), 16-ch slice bc -> 8 corner loads, 2 writes
  const int bn = tid >> 2;
  const int bc = (tid & 3) * 16;
  const int s = s0 + bn;
  const unsigned swb = (unsigned)(bn & 7) << 4;
  const unsigned short* xb = XH + b * (64 * 64 * 256);

  f32x4 acc[4][4];
#pragma unroll
  for (int i = 0; i < 4; ++i)
#pragma unroll
    for (int j = 0; j < 4; ++j) acc[i][j] = (f32x4){0.f, 0.f, 0.f, 0.f};

  u32x4 ar[2];
  u32x4 o0, o1;
  Bld16 bld;

  // prologue: tile 0 -> regs -> buffer 0
  ar[0] = *(const u32x4*)(arow);
  ar[1] = *(const u32x4*)(arow + 8);
  loadB16(xb, W4, C4, b, 0, 0, bc, s, bld);
  blendB16(bld, o0, o1);
  {
    unsigned char* ldsA = ldsbase;
    unsigned char* ldsB = ldsbase + 16384;
    const unsigned abase = (unsigned)am * 128u;
    *(u32x4*)(ldsA + abase + (((unsigned)(ah * 32)) ^ swa)) = ar[0];
    *(u32x4*)(ldsA + abase + (((unsigned)(ah * 32 + 16)) ^ swa)) = ar[1];
    const unsigned bbase = (unsigned)bn * 128u;
    *(u32x4*)(ldsB + bbase + (((unsigned)(bc * 2)) ^ swb)) = o0;
    *(u32x4*)(ldsB + bbase + (((unsigned)(bc * 2 + 16)) ^ swb)) = o1;
  }

  for (int ks = 0; ks < 36; ++ks) {
    const int cur = ks & 1;
    unsigned char* ldsA = ldsbase + cur * 32768;
    unsigned char* ldsB = ldsA + 16384;
    unsigned char* ldsAn = ldsbase + (cur ^ 1) * 32768;
    unsigned char* ldsBn = ldsAn + 16384;

    __syncthreads();  // buf[cur] writes visible; buf[cur^1] reads (iter ks-1) done

    // prefetch next tile's globals (fly under the MFMA cluster)
    if (ks + 1 < 36) {
      int kn = (ks + 1) >> 2, cn = ((ks + 1) & 3) << 6;
      ar[0] = *(const u32x4*)(arow + kn * 256 + cn);
      ar[1] = *(const u32x4*)(arow + kn * 256 + cn + 8);
      loadB16(xb, W4, C4, b, kn, cn, bc, s, bld);
    }

    // each wave computes only its K-half (kk) of this K-step
    {
      bf16x8 af[4], bfr[4];
      const unsigned co = (unsigned)(kk * 64 + ((l >> 4) * 16));
#pragma unroll
      for (int i = 0; i < 4; ++i) {
        int row = wm + i * 16 + (l & 15);
        af[i] = *(const bf16x8*)(ldsA + (unsigned)row * 128u +
                                 (co ^ ((unsigned)(row & 7) << 4)));
      }
#pragma unroll
      for (int j = 0; j < 4; ++j) {
        int col = wn + j * 16 + (l & 15);
        bfr[j] = *(const bf16x8*)(ldsB + (unsigned)col * 128u +
                                  (co ^ ((unsigned)(col & 7) << 4)));
      }
#pragma unroll
      for (int i = 0; i < 4; ++i)
#pragma unroll
        for (int j = 0; j < 4; ++j)
          acc[i][j] = __builtin_amdgcn_mfma_f32_16x16x32_bf16(af[i], bfr[j],
                                                              acc[i][j], 0, 0, 0);
    }

    // blend + write next tile into the other buffer (read side untouched)
    if (ks + 1 < 36) {
      blendB16(bld, o0, o1);
      const unsigned abase = (unsigned)am * 128u;
      *(u32x4*)(ldsAn + abase + (((unsigned)(ah * 32)) ^ swa)) = ar[0];
      *(u32x4*)(ldsAn + abase + (((unsigned)(ah * 32 + 16)) ^ swa)) = ar[1];
      const unsigned bbase = (unsigned)bn * 128u;
      *(u32x4*)(ldsBn + bbase + (((unsigned)(bc * 2)) ^ swb)) = o0;
      *(u32x4*)(ldsBn + bbase + (((unsigned)(bc * 2 + 16)) ^ swb)) = o1;
    }
  }

  // ---- merge K-half partials: kk=1 waves publish, kk=0 waves accumulate ----
  __syncthreads();  // all MFMA LDS reads done; safe to reuse LDS
#pragma unroll
  for (int r = 0; r < 2; ++r) {
    if (kk == 1) {
#pragma unroll
      for (int v = 0; v < 8; ++v) {
        int i = 2 * r + (v >> 2), j = v & 3;
        unsigned addr = (unsigned)sw * 8192u + (unsigned)l * 128u +
                        (unsigned)((v ^ (l & 7)) * 16);
        *(f32x4*)(ldsbase + addr) = acc[i][j];
      }
    }
    __syncthreads();
    if (kk == 0) {
#pragma unroll
      for (int v = 0; v < 8; ++v) {
        int i = 2 * r + (v >> 2), j = v & 3;
        unsigned addr = (unsigned)sw * 8192u + (unsigned)l * 128u +
                        (unsigned)((v ^ (l & 7)) * 16);
        f32x4 p = *(const f32x4*)(ldsbase + addr);
        acc[i][j] += p;
      }
    }
    __syncthreads();
  }

  // epilogue (kk=0 waves only): D layout col=lane&15, row=(lane>>4)*4+reg (m89)
  if (kk == 0) {
    const int cn2 = l & 15;
    const int r0 = (l >> 4) * 4;
#pragma unroll
    for (int i = 0; i < 4; ++i) {
#pragma unroll
      for (int j = 0; j < 4; ++j) {
        int sc = s0 + wn + j * 16 + cn2;
#pragma unroll
        for (int rr = 0; rr < 4; ++rr) {
          int o = mh * 128 + wm + i * 16 + r0 + rr;
          out[((b * 256 + o) << 12) + sc] = acc[i][j][rr];
        }
      }
    }
  }
}

extern "C" void kernel_launch(void* const* d_in, const int* in_sizes, int n_in,
                              void* d_out, int out_size, void* d_ws, size_t ws_size,
                              hipStream_t stream) {
  const float* x = (const float*)d_in[0];
  const float* wof = (const float*)d_in[1];
  const float* wc = (const float*)d_in[2];
  float* out = (float*)d_out;
  char* ws = (char*)d_ws;

  // ws layout (total 27.7 MB — proven available in round 8)
  unsigned short* XH = (unsigned short*)(ws);              // 16,777,216 B
  unsigned short* AW = (unsigned short*)(ws + 16777216);   //  1,179,648 B
  unsigned short* AOH = (unsigned short*)(ws + 17956864);  //    147,456 B
  unsigned short* AOL = (unsigned short*)(ws + 18104320);  //    147,456 B
  float* PY = (float*)(ws + 18251776);                     //  1,179,648 B
  float* PX = (float*)(ws + 19431424);                     //  1,179,648 B
  float* MS = (float*)(ws + 20611072);                     //  1,179,648 B
  f32x4* W4 = (f32x4*)(ws + 21790720);                     //  4,718,592 B
  unsigned* C4 = (unsigned*)(ws + 26509312);               //  1,179,648 B (end 27,688,960)

  // XL (bf16 residual of x, NHWC, 16 MB) lives in d_out: only read by
  // k_offc_mfma, which completes before k_gemm overwrites d_out.
  unsigned short* XL = (unsigned short*)d_out;

  k_nhwc<<<512, 256, 0, stream>>>(x, XH, XL);
  k_wprep<<<2304, 256, 0, stream>>>(wc, AW);
  k_wprep_off<<<288, 256, 0, stream>>>(wof, AOH, AOL);
  k_offc_mfma<<<512, 256, 0, stream>>>(AOH, AOL, XH, XL, PY, PX, MS);
  k_xform3<<<1152, 256, 0, stream>>>(PY, PX, MS, W4, C4);
  k_gemm<<<512, 512, 0, stream>>>(AW, XH, W4, C4, out);
}

// Round 10
// 238.073 us; speedup vs baseline: 1.0921x; 1.0921x over previous
//
#include <hip/hip_runtime.h>
#include <hip/hip_bf16.h>

typedef float f32x4 __attribute__((ext_vector_type(4)));
typedef unsigned int u32x4 __attribute__((ext_vector_type(4)));
typedef __bf16 bf16x8 __attribute__((ext_vector_type(8)));

#define NSP 4096
#define KTOT 2304

static __device__ __forceinline__ float bflo(unsigned u) {
  return __builtin_bit_cast(float, u << 16);
}
static __device__ __forceinline__ float bfhi(unsigned u) {
  return __builtin_bit_cast(float, u & 0xffff0000u);
}
static __device__ __forceinline__ unsigned short bfbits(float f) {
  return __builtin_bit_cast(unsigned short, (__bf16)f);
}
static __device__ __forceinline__ unsigned packbf2(float f0, float f1) {
  return (unsigned)bfbits(f0) | ((unsigned)bfbits(f1) << 16);
}
static __device__ __forceinline__ float bf16f(unsigned short h) {
  return __builtin_bit_cast(float, (unsigned)h << 16);
}

// ---------- x (B,C,H,W) f32 -> XH (B,H,W,C) bf16 hi + XL bf16 residual ----------
__global__ __launch_bounds__(256) void k_nhwc(const float* __restrict__ x,
                                              unsigned short* __restrict__ XH,
                                              unsigned short* __restrict__ XL) {
  const int by = blockIdx.x;            // b*64 + y
  const int t = threadIdx.x;
  const int xw = t & 63;
  const int cq = t >> 6;                // 0..3
  const float* xp = x + (((by >> 6) * 256 * 64 + (by & 63)) * 64 + xw);
  unsigned short* oh = XH + (by * 64 + xw) * 256;
  unsigned short* ol = XL + (by * 64 + xw) * 256;
#pragma unroll
  for (int j8 = 0; j8 < 8; ++j8) {
    const int c0 = cq * 64 + j8 * 8;
    u32x4 vh, vl;
#pragma unroll
    for (int d = 0; d < 4; ++d) {
      float f0 = xp[(c0 + 2 * d) * 4096];
      float f1 = xp[(c0 + 2 * d + 1) * 4096];
      unsigned short h0 = bfbits(f0), h1 = bfbits(f1);
      float r0 = f0 - bf16f(h0);
      float r1 = f1 - bf16f(h1);
      vh[d] = (unsigned)h0 | ((unsigned)h1 << 16);
      vl[d] = packbf2(r0, r1);
    }
    *(u32x4*)(oh + c0) = vh;
    *(u32x4*)(ol + c0) = vl;
  }
}

// ---------- w_conv (Co,C,3,3) f32 -> AW (Co, k*256+c) bf16 ----------
__global__ void k_wprep(const float* __restrict__ wc, unsigned short* __restrict__ AW) {
  int idx = blockIdx.x * 256 + threadIdx.x;
  if (idx >= 256 * KTOT) return;
  int o = idx / KTOT;
  int r = idx - o * KTOT;
  int k = r >> 8, c = r & 255;
  AW[idx] = bfbits(wc[(o * 256 + c) * 9 + k]);
}

// ---------- w_offset (27,256,3,3) f32 -> AOH/AOL [32][tap*256+c] bf16 hi/lo ----------
__global__ void k_wprep_off(const float* __restrict__ wof,
                            unsigned short* __restrict__ AOH,
                            unsigned short* __restrict__ AOL) {
  int idx = blockIdx.x * 256 + threadIdx.x;   // 32*2304 = 73728
  if (idx >= 32 * KTOT) return;
  int m = idx / KTOT;
  int r = idx - m * KTOT;
  int t = r >> 8, c = r & 255;
  float v = (m < 27) ? wof[(m * 256 + c) * 9 + t] : 0.f;
  unsigned short h = bfbits(v);
  AOH[idx] = h;
  AOL[idx] = bfbits(v - bf16f(h));
}

// ---------- offset conv via split-bf16 MFMA, K split across 2 blocks ----------
__global__ __launch_bounds__(256) void k_offc_mfma(const unsigned short* __restrict__ AOH,
                                                   const unsigned short* __restrict__ AOL,
                                                   const unsigned short* __restrict__ XH,
                                                   const unsigned short* __restrict__ XL,
                                                   float* __restrict__ PY,
                                                   float* __restrict__ PX,
                                                   float* __restrict__ MS) {
  const int tid = threadIdx.x;
  const int l = tid & 63;
  const int w = tid >> 6;                 // 4 waves, each owns 16 cols
  const int bid = blockIdx.x;             // b(8) x y(64) x kh(2)
  const int b = bid & 7;                  // XCD swizzle: one batch per XCD
  const int y = (bid >> 3) & 63;
  const int kh = bid >> 9;                // channel half: kh*128 ..
  const int xcol = w * 16 + (l & 15);
  const int kq = kh * 128 + (l >> 4) * 8;
  const unsigned short* xb = XH + b * (64 * 64 * 256);
  const unsigned short* xlb = XL + b * (64 * 64 * 256);
  const int mr = l & 15;

  f32x4 acc0 = (f32x4){0.f, 0.f, 0.f, 0.f};
  f32x4 acc1 = (f32x4){0.f, 0.f, 0.f, 0.f};

#pragma unroll
  for (int tap = 0; tap < 9; ++tap) {
    const int yy = y + tap / 3 - 1;
    const int xx = xcol + tap % 3 - 1;
    const bool valid = ((unsigned)yy < 64u) & ((unsigned)xx < 64u);
    const unsigned short* bp = xb + (yy * 64 + xx) * 256 + kq;
    const unsigned short* blp = xlb + (yy * 64 + xx) * 256 + kq;
    const unsigned short* a0 = AOH + mr * KTOT + tap * 256 + kq;
    const unsigned short* a1 = AOH + (mr + 16) * KTOT + tap * 256 + kq;
    const unsigned short* c0p = AOL + mr * KTOT + tap * 256 + kq;
    const unsigned short* c1p = AOL + (mr + 16) * KTOT + tap * 256 + kq;
#pragma unroll
    for (int kc = 0; kc < 4; ++kc) {
      u32x4 zh = (u32x4){0u, 0u, 0u, 0u};
      u32x4 bhu = valid ? *(const u32x4*)(bp + kc * 32) : zh;
      u32x4 blu = valid ? *(const u32x4*)(blp + kc * 32) : zh;
      bf16x8 bh = __builtin_bit_cast(bf16x8, bhu);
      bf16x8 bl = __builtin_bit_cast(bf16x8, blu);
      bf16x8 ah0 = *(const bf16x8*)(a0 + kc * 32);
      bf16x8 ah1 = *(const bf16x8*)(a1 + kc * 32);
      bf16x8 al0 = *(const bf16x8*)(c0p + kc * 32);
      bf16x8 al1 = *(const bf16x8*)(c1p + kc * 32);
      acc0 = __builtin_amdgcn_mfma_f32_16x16x32_bf16(ah0, bh, acc0, 0, 0, 0);
      acc1 = __builtin_amdgcn_mfma_f32_16x16x32_bf16(ah1, bh, acc1, 0, 0, 0);
      acc0 = __builtin_amdgcn_mfma_f32_16x16x32_bf16(ah0, bl, acc0, 0, 0, 0);
      acc1 = __builtin_amdgcn_mfma_f32_16x16x32_bf16(ah1, bl, acc1, 0, 0, 0);
      acc0 = __builtin_amdgcn_mfma_f32_16x16x32_bf16(al0, bh, acc0, 0, 0, 0);
      acc1 = __builtin_amdgcn_mfma_f32_16x16x32_bf16(al1, bh, acc1, 0, 0, 0);
    }
  }

  // D layout: col=lane&15 (=our n), row=(lane>>4)*4+reg; atomic-accumulate halves
  const int s = y * 64 + xcol;
#pragma unroll
  for (int mf = 0; mf < 2; ++mf) {
    f32x4 a = mf ? acc1 : acc0;
#pragma unroll
    for (int r = 0; r < 4; ++r) {
      int m = mf * 16 + (l >> 4) * 4 + r;
      if (m < 27) {
        int which = m / 9;
        int mm = m - which * 9;
        float* dst = which == 0 ? PY : (which == 1 ? PX : MS);
        atomicAdd(&dst[((b * 9 + mm) << 12) + s], a[r]);
      }
    }
  }
}

// ---------- precompute bilinear metadata: weights (masked) + packed corner idx ----------
__global__ void k_xform3(const float* __restrict__ PY, const float* __restrict__ PX,
                         const float* __restrict__ MS, f32x4* __restrict__ W4,
                         unsigned* __restrict__ C4) {
  int idx = blockIdx.x * 256 + threadIdx.x;   // (b*9+k)*4096 + s
  if (idx >= 8 * 9 * NSP) return;
  int s = idx & 4095;
  int k = (idx >> 12) % 9;
  float py = PY[idx] + (float)(s >> 6) - 1.f + (float)(k / 3);
  float px = PX[idx] + (float)(s & 63) - 1.f + (float)(k % 3);
  float mk = 1.f / (1.f + __expf(-MS[idx]));

  float y0f = floorf(py), x0f = floorf(px);
  float ly = py - y0f, lx = px - x0f;
  int y0 = (int)y0f, x0 = (int)x0f;
  int y1 = y0 + 1, x1 = x0 + 1;
  float omy = 1.f - ly, omx = 1.f - lx;
  bool y0v = (unsigned)y0 < 64u, y1v = (unsigned)y1 < 64u;
  bool x0v = (unsigned)x0 < 64u, x1v = (unsigned)x1 < 64u;
  f32x4 wv;
  wv[0] = (y0v && x0v) ? omy * omx * mk : 0.f;
  wv[1] = (y0v && x1v) ? omy * lx * mk : 0.f;
  wv[2] = (y1v && x0v) ? ly * omx * mk : 0.f;
  wv[3] = (y1v && x1v) ? ly * lx * mk : 0.f;
  int y0c = min(max(y0, 0), 63), y1c = min(max(y1, 0), 63);
  int x0c = min(max(x0, 0), 63), x1c = min(max(x1, 0), 63);
  unsigned p00 = (unsigned)(y0c * 64 + x0c);
  unsigned p11 = (unsigned)(y1c * 64 + x1c);
  W4[idx] = wv;
  C4[idx] = p00 | (p11 << 16);
}

// ---------- fused sampling + implicit GEMM (round-2 structure + W4/C4) ----------
struct Bld16 {
  u32x4 g00a, g00b, g01a, g01b, g10a, g10b, g11a, g11b;
  f32x4 wv;
};

static __device__ __forceinline__ void loadB16(const unsigned short* __restrict__ xb,
                                               const f32x4* __restrict__ W4,
                                               const unsigned* __restrict__ C4,
                                               int b, int k, int c0, int bc, int s,
                                               Bld16& r) {
  int ci = (b * 9 + k) * NSP + s;
  r.wv = W4[ci];
  unsigned c4 = C4[ci];
  unsigned p00 = c4 & 0xffffu, p11 = c4 >> 16;
  unsigned p01 = (p00 & ~63u) | (p11 & 63u);
  unsigned p10 = (p11 & ~63u) | (p00 & 63u);
  const unsigned short* base = xb + (c0 + bc);
  const unsigned short* q00 = base + (p00 << 8);
  const unsigned short* q01 = base + (p01 << 8);
  const unsigned short* q10 = base + (p10 << 8);
  const unsigned short* q11 = base + (p11 << 8);
  r.g00a = *(const u32x4*)q00;
  r.g00b = *(const u32x4*)(q00 + 8);
  r.g01a = *(const u32x4*)q01;
  r.g01b = *(const u32x4*)(q01 + 8);
  r.g10a = *(const u32x4*)q10;
  r.g10b = *(const u32x4*)(q10 + 8);
  r.g11a = *(const u32x4*)q11;
  r.g11b = *(const u32x4*)(q11 + 8);
}

static __device__ __forceinline__ void blendB16(const Bld16& r, u32x4& o0, u32x4& o1) {
#pragma unroll
  for (int d = 0; d < 4; ++d) {
    float a0 = r.wv[0] * bflo(r.g00a[d]) + r.wv[1] * bflo(r.g01a[d]) +
               r.wv[2] * bflo(r.g10a[d]) + r.wv[3] * bflo(r.g11a[d]);
    float a1 = r.wv[0] * bfhi(r.g00a[d]) + r.wv[1] * bfhi(r.g01a[d]) +
               r.wv[2] * bfhi(r.g10a[d]) + r.wv[3] * bfhi(r.g11a[d]);
    o0[d] = packbf2(a0, a1);
    float b0 = r.wv[0] * bflo(r.g00b[d]) + r.wv[1] * bflo(r.g01b[d]) +
               r.wv[2] * bflo(r.g10b[d]) + r.wv[3] * bflo(r.g11b[d]);
    float b1 = r.wv[0] * bfhi(r.g00b[d]) + r.wv[1] * bfhi(r.g01b[d]) +
               r.wv[2] * bfhi(r.g10b[d]) + r.wv[3] * bfhi(r.g11b[d]);
    o1[d] = packbf2(b0, b1);
  }
}

__global__ __launch_bounds__(512) void k_gemm(const unsigned short* __restrict__ AW,
                                              const unsigned short* __restrict__ XH,
                                              const f32x4* __restrict__ W4,
                                              const unsigned* __restrict__ C4,
                                              float* __restrict__ out) {
  __shared__ u32x4 ldsA4[2048];  // 32 KB: A tile [256 rows][64 bf16], 16B-XOR swizzled
  __shared__ u32x4 ldsB4[1024];  // 16 KB: B tile [128 rows][64 bf16]
  unsigned char* ldsA = (unsigned char*)ldsA4;
  unsigned char* ldsB = (unsigned char*)ldsB4;

  const int tid = threadIdx.x;
  const int bid = blockIdx.x;
  const int b = bid >> 5;          // round-2 exact block mapping
  const int s0 = (bid & 31) * 128;

  const int l = tid & 63;
  const int w = tid >> 6;
  const int wm = (w >> 1) * 64;  // 4 M-waves
  const int wn = (w & 1) * 64;   // 2 N-waves

  const int am = tid & 255;
  const int ah = tid >> 8;
  const unsigned short* arow = AW + am * KTOT + ah * 32;
  const unsigned swa = (unsigned)(am & 7) << 4;

  const int bn = tid >> 2;
  const int bc = (tid & 3) * 16;
  const int s = s0 + bn;
  const unsigned swb = (unsigned)(bn & 7) << 4;
  const unsigned short* xb = XH + b * (64 * 64 * 256);

  f32x4 acc[4][4];
#pragma unroll
  for (int i = 0; i < 4; ++i)
#pragma unroll
    for (int j = 0; j < 4; ++j) acc[i][j] = (f32x4){0.f, 0.f, 0.f, 0.f};

  for (int ks = 0; ks < 36; ++ks) {
    const int kn = ks >> 2, cn = (ks & 3) << 6;

    // plain staging (round-2 structure): global loads -> regs -> blend
    u32x4 ar[4];
#pragma unroll
    for (int j = 0; j < 4; ++j)
      ar[j] = *(const u32x4*)(arow + kn * 256 + cn + j * 8);
    Bld16 bld;
    loadB16(xb, W4, C4, b, kn, cn, bc, s, bld);
    u32x4 o0, o1;
    blendB16(bld, o0, o1);

    __syncthreads();  // previous iteration's MFMA reads done
    {
      const unsigned abase = (unsigned)am * 128u;
#pragma unroll
      for (int j = 0; j < 4; ++j)
        *(u32x4*)(ldsA + abase + (((unsigned)(ah * 64 + j * 16)) ^ swa)) = ar[j];
      const unsigned bbase = (unsigned)bn * 128u;
      *(u32x4*)(ldsB + bbase + (((unsigned)(bc * 2)) ^ swb)) = o0;
      *(u32x4*)(ldsB + bbase + (((unsigned)(bc * 2 + 16)) ^ swb)) = o1;
    }
    __syncthreads();

#pragma unroll
    for (int kk = 0; kk < 2; ++kk) {
      bf16x8 af[4], bfr[4];
      const unsigned co = (unsigned)(kk * 64 + ((l >> 4) * 16));
#pragma unroll
      for (int i = 0; i < 4; ++i) {
        int row = wm + i * 16 + (l & 15);
        af[i] = *(const bf16x8*)(ldsA + (unsigned)row * 128u +
                                 (co ^ ((unsigned)(row & 7) << 4)));
      }
#pragma unroll
      for (int j = 0; j < 4; ++j) {
        int col = wn + j * 16 + (l & 15);
        bfr[j] = *(const bf16x8*)(ldsB + (unsigned)col * 128u +
                                  (co ^ ((unsigned)(col & 7) << 4)));
      }
#pragma unroll
      for (int i = 0; i < 4; ++i)
#pragma unroll
        for (int j = 0; j < 4; ++j)
          acc[i][j] = __builtin_amdgcn_mfma_f32_16x16x32_bf16(af[i], bfr[j],
                                                              acc[i][j], 0, 0, 0);
    }
  }

  // epilogue: D layout col=lane&15, row=(lane>>4)*4+reg (m89)
  const int cn2 = l & 15;
  const int r0 = (l >> 4) * 4;
#pragma unroll
  for (int i = 0; i < 4; ++i) {
#pragma unroll
    for (int j = 0; j < 4; ++j) {
      int sc = s0 + wn + j * 16 + cn2;
#pragma unroll
      for (int r = 0; r < 4; ++r) {
        int o = wm + i * 16 + r0 + r;
        out[((b * 256 + o) << 12) + sc] = acc[i][j][r];
      }
    }
  }
}

extern "C" void kernel_launch(void* const* d_in, const int* in_sizes, int n_in,
                              void* d_out, int out_size, void* d_ws, size_t ws_size,
                              hipStream_t stream) {
  const float* x = (const float*)d_in[0];
  const float* wof = (const float*)d_in[1];
  const float* wc = (const float*)d_in[2];
  float* out = (float*)d_out;
  char* ws = (char*)d_ws;

  // ws layout (total 27.7 MB — proven available)
  unsigned short* XH = (unsigned short*)(ws);              // 16,777,216 B
  unsigned short* AW = (unsigned short*)(ws + 16777216);   //  1,179,648 B
  unsigned short* AOH = (unsigned short*)(ws + 17956864);  //    147,456 B
  unsigned short* AOL = (unsigned short*)(ws + 18104320);  //    147,456 B
  float* PY = (float*)(ws + 18251776);                     //  1,179,648 B
  float* PX = (float*)(ws + 19431424);                     //  1,179,648 B
  float* MS = (float*)(ws + 20611072);                     //  1,179,648 B
  f32x4* W4 = (f32x4*)(ws + 21790720);                     //  4,718,592 B
  unsigned* C4 = (unsigned*)(ws + 26509312);               //  1,179,648 B (end 27,688,960)

  // XL (bf16 residual of x, NHWC, 16 MB) lives in d_out: only read by
  // k_offc_mfma, which completes before k_gemm overwrites d_out.
  unsigned short* XL = (unsigned short*)d_out;

  hipMemsetAsync(ws + 18251776, 0, 3 * 1179648, stream);  // zero PY/PX/MS (atomic targets)
  k_nhwc<<<512, 256, 0, stream>>>(x, XH, XL);
  k_wprep<<<2304, 256, 0, stream>>>(wc, AW);
  k_wprep_off<<<288, 256, 0, stream>>>(wof, AOH, AOL);
  k_offc_mfma<<<1024, 256, 0, stream>>>(AOH, AOL, XH, XL, PY, PX, MS);
  k_xform3<<<1152, 256, 0, stream>>>(PY, PX, MS, W4, C4);
  k_gemm<<<256, 512, 0, stream>>>(AW, XH, W4, C4, out);
}

// Round 11
// 218.882 us; speedup vs baseline: 1.1879x; 1.0877x over previous
//
#include <hip/hip_runtime.h>
#include <hip/hip_bf16.h>

typedef float f32x4 __attribute__((ext_vector_type(4)));
typedef unsigned int u32x4 __attribute__((ext_vector_type(4)));
typedef __bf16 bf16x8 __attribute__((ext_vector_type(8)));

#define NSP 4096
#define KTOT 2304
#define PSTRIDE 294912  // 8*9*4096 floats per partial array

static __device__ __forceinline__ float bflo(unsigned u) {
  return __builtin_bit_cast(float, u << 16);
}
static __device__ __forceinline__ float bfhi(unsigned u) {
  return __builtin_bit_cast(float, u & 0xffff0000u);
}
static __device__ __forceinline__ unsigned short bfbits(float f) {
  return __builtin_bit_cast(unsigned short, (__bf16)f);
}
static __device__ __forceinline__ unsigned packbf2(float f0, float f1) {
  return (unsigned)bfbits(f0) | ((unsigned)bfbits(f1) << 16);
}
static __device__ __forceinline__ float bf16f(unsigned short h) {
  return __builtin_bit_cast(float, (unsigned)h << 16);
}

// ---------- x (B,C,H,W) f32 -> XH (B,H,W,C) bf16 hi + XL bf16 residual ----------
__global__ __launch_bounds__(256) void k_nhwc(const float* __restrict__ x,
                                              unsigned short* __restrict__ XH,
                                              unsigned short* __restrict__ XL) {
  const int by = blockIdx.x;            // b*64 + y
  const int t = threadIdx.x;
  const int xw = t & 63;
  const int cq = t >> 6;                // 0..3
  const float* xp = x + (((by >> 6) * 256 * 64 + (by & 63)) * 64 + xw);
  unsigned short* oh = XH + (by * 64 + xw) * 256;
  unsigned short* ol = XL + (by * 64 + xw) * 256;
#pragma unroll
  for (int j8 = 0; j8 < 8; ++j8) {
    const int c0 = cq * 64 + j8 * 8;
    u32x4 vh, vl;
#pragma unroll
    for (int d = 0; d < 4; ++d) {
      float f0 = xp[(c0 + 2 * d) * 4096];
      float f1 = xp[(c0 + 2 * d + 1) * 4096];
      unsigned short h0 = bfbits(f0), h1 = bfbits(f1);
      float r0 = f0 - bf16f(h0);
      float r1 = f1 - bf16f(h1);
      vh[d] = (unsigned)h0 | ((unsigned)h1 << 16);
      vl[d] = packbf2(r0, r1);
    }
    *(u32x4*)(oh + c0) = vh;
    *(u32x4*)(ol + c0) = vl;
  }
}

// ---------- w_conv (Co,C,3,3) f32 -> AW (Co, k*256+c) bf16 ----------
__global__ void k_wprep(const float* __restrict__ wc, unsigned short* __restrict__ AW) {
  int idx = blockIdx.x * 256 + threadIdx.x;
  if (idx >= 256 * KTOT) return;
  int o = idx / KTOT;
  int r = idx - o * KTOT;
  int k = r >> 8, c = r & 255;
  AW[idx] = bfbits(wc[(o * 256 + c) * 9 + k]);
}

// ---------- w_offset (27,256,3,3) f32 -> AOH/AOL [32][tap*256+c] bf16 hi/lo ----------
__global__ void k_wprep_off(const float* __restrict__ wof,
                            unsigned short* __restrict__ AOH,
                            unsigned short* __restrict__ AOL) {
  int idx = blockIdx.x * 256 + threadIdx.x;   // 32*2304 = 73728
  if (idx >= 32 * KTOT) return;
  int m = idx / KTOT;
  int r = idx - m * KTOT;
  int t = r >> 8, c = r & 255;
  float v = (m < 27) ? wof[(m * 256 + c) * 9 + t] : 0.f;
  unsigned short h = bfbits(v);
  AOH[idx] = h;
  AOL[idx] = bfbits(v - bf16f(h));
}

// ---------- offset conv, split-bf16 MFMA, 4-way channel split, partial outputs ----------
__global__ __launch_bounds__(256, 8) void k_offc_mfma(
    const unsigned short* __restrict__ AOH, const unsigned short* __restrict__ AOL,
    const unsigned short* __restrict__ XH, const unsigned short* __restrict__ XL,
    float* __restrict__ P0) {
  const int tid = threadIdx.x;
  const int l = tid & 63;
  const int w = tid >> 6;                 // 4 waves, each owns 16 cols
  const int bid = blockIdx.x;             // b(8) x y(64) x kh(4)
  const int b = bid & 7;                  // XCD swizzle: one batch per XCD
  const int y = (bid >> 3) & 63;
  const int kh = bid >> 9;                // channel quarter: kh*64 ..
  const int xcol = w * 16 + (l & 15);
  const int kq = kh * 64 + (l >> 4) * 8;
  const unsigned short* xb = XH + b * (64 * 64 * 256);
  const unsigned short* xlb = XL + b * (64 * 64 * 256);
  const int mr = l & 15;

  f32x4 acc0 = (f32x4){0.f, 0.f, 0.f, 0.f};
  f32x4 acc1 = (f32x4){0.f, 0.f, 0.f, 0.f};

#pragma unroll
  for (int tap = 0; tap < 9; ++tap) {
    const int yy = y + tap / 3 - 1;
    const int xx = xcol + tap % 3 - 1;
    const bool valid = ((unsigned)yy < 64u) & ((unsigned)xx < 64u);
    const unsigned short* bp = xb + (yy * 64 + xx) * 256 + tap * 0 + kq;
    const unsigned short* blp = xlb + (yy * 64 + xx) * 256 + kq;
    const unsigned short* a0 = AOH + mr * KTOT + tap * 256 + kq;
    const unsigned short* a1 = AOH + (mr + 16) * KTOT + tap * 256 + kq;
    const unsigned short* c0p = AOL + mr * KTOT + tap * 256 + kq;
    const unsigned short* c1p = AOL + (mr + 16) * KTOT + tap * 256 + kq;
#pragma unroll
    for (int kc = 0; kc < 2; ++kc) {
      u32x4 zh = (u32x4){0u, 0u, 0u, 0u};
      u32x4 bhu = valid ? *(const u32x4*)(bp + kc * 32) : zh;
      u32x4 blu = valid ? *(const u32x4*)(blp + kc * 32) : zh;
      bf16x8 bh = __builtin_bit_cast(bf16x8, bhu);
      bf16x8 bl = __builtin_bit_cast(bf16x8, blu);
      bf16x8 ah0 = *(const bf16x8*)(a0 + kc * 32);
      bf16x8 ah1 = *(const bf16x8*)(a1 + kc * 32);
      bf16x8 al0 = *(const bf16x8*)(c0p + kc * 32);
      bf16x8 al1 = *(const bf16x8*)(c1p + kc * 32);
      acc0 = __builtin_amdgcn_mfma_f32_16x16x32_bf16(ah0, bh, acc0, 0, 0, 0);
      acc1 = __builtin_amdgcn_mfma_f32_16x16x32_bf16(ah1, bh, acc1, 0, 0, 0);
      acc0 = __builtin_amdgcn_mfma_f32_16x16x32_bf16(ah0, bl, acc0, 0, 0, 0);
      acc1 = __builtin_amdgcn_mfma_f32_16x16x32_bf16(ah1, bl, acc1, 0, 0, 0);
      acc0 = __builtin_amdgcn_mfma_f32_16x16x32_bf16(al0, bh, acc0, 0, 0, 0);
      acc1 = __builtin_amdgcn_mfma_f32_16x16x32_bf16(al1, bh, acc1, 0, 0, 0);
    }
  }

  // D layout: col=lane&15 (=our n), row=(lane>>4)*4+reg; plain store to partial[kh]
  const int s = y * 64 + xcol;
  float* Pk = P0 + kh * 3 * PSTRIDE;
#pragma unroll
  for (int mf = 0; mf < 2; ++mf) {
    f32x4 a = mf ? acc1 : acc0;
#pragma unroll
    for (int r = 0; r < 4; ++r) {
      int m = mf * 16 + (l >> 4) * 4 + r;
      if (m < 27) {
        int which = m / 9;
        int mm = m - which * 9;
        Pk[which * PSTRIDE + ((b * 9 + mm) << 12) + s] = a[r];
      }
    }
  }
}

// ---------- reduce 4 partials + base grid + sigmoid -> W4/C4 metadata ----------
__global__ void k_xform3(const float* __restrict__ P0, f32x4* __restrict__ W4,
                         unsigned* __restrict__ C4) {
  int idx = blockIdx.x * 256 + threadIdx.x;   // (b*9+k)*4096 + s
  if (idx >= 8 * 9 * NSP) return;
  int s = idx & 4095;
  int k = (idx >> 12) % 9;
  float oy = 0.f, ox = 0.f, lg = 0.f;
#pragma unroll
  for (int kh = 0; kh < 4; ++kh) {
    const float* Pk = P0 + kh * 3 * PSTRIDE;
    oy += Pk[idx];
    ox += Pk[PSTRIDE + idx];
    lg += Pk[2 * PSTRIDE + idx];
  }
  float py = oy + (float)(s >> 6) - 1.f + (float)(k / 3);
  float px = ox + (float)(s & 63) - 1.f + (float)(k % 3);
  float mk = 1.f / (1.f + __expf(-lg));

  float y0f = floorf(py), x0f = floorf(px);
  float ly = py - y0f, lx = px - x0f;
  int y0 = (int)y0f, x0 = (int)x0f;
  int y1 = y0 + 1, x1 = x0 + 1;
  float omy = 1.f - ly, omx = 1.f - lx;
  bool y0v = (unsigned)y0 < 64u, y1v = (unsigned)y1 < 64u;
  bool x0v = (unsigned)x0 < 64u, x1v = (unsigned)x1 < 64u;
  f32x4 wv;
  wv[0] = (y0v && x0v) ? omy * omx * mk : 0.f;
  wv[1] = (y0v && x1v) ? omy * lx * mk : 0.f;
  wv[2] = (y1v && x0v) ? ly * omx * mk : 0.f;
  wv[3] = (y1v && x1v) ? ly * lx * mk : 0.f;
  int y0c = min(max(y0, 0), 63), y1c = min(max(y1, 0), 63);
  int x0c = min(max(x0, 0), 63), x1c = min(max(x1, 0), 63);
  unsigned p00 = (unsigned)(y0c * 64 + x0c);
  unsigned p11 = (unsigned)(y1c * 64 + x1c);
  W4[idx] = wv;
  C4[idx] = p00 | (p11 << 16);
}

// ---------- fused sampling + implicit GEMM (r5 dbuf structure + W4/C4) ----------
struct Bld16 {
  u32x4 g00a, g00b, g01a, g01b, g10a, g10b, g11a, g11b;
  f32x4 wv;
};

static __device__ __forceinline__ void loadB16(const unsigned short* __restrict__ xb,
                                               const f32x4* __restrict__ W4,
                                               const unsigned* __restrict__ C4,
                                               int b, int k, int c0, int bc, int s,
                                               Bld16& r) {
  int ci = (b * 9 + k) * NSP + s;
  r.wv = W4[ci];
  unsigned c4 = C4[ci];
  unsigned p00 = c4 & 0xffffu, p11 = c4 >> 16;
  unsigned p01 = (p00 & ~63u) | (p11 & 63u);
  unsigned p10 = (p11 & ~63u) | (p00 & 63u);
  const unsigned short* base = xb + (c0 + bc);
  const unsigned short* q00 = base + (p00 << 8);
  const unsigned short* q01 = base + (p01 << 8);
  const unsigned short* q10 = base + (p10 << 8);
  const unsigned short* q11 = base + (p11 << 8);
  r.g00a = *(const u32x4*)q00;
  r.g00b = *(const u32x4*)(q00 + 8);
  r.g01a = *(const u32x4*)q01;
  r.g01b = *(const u32x4*)(q01 + 8);
  r.g10a = *(const u32x4*)q10;
  r.g10b = *(const u32x4*)(q10 + 8);
  r.g11a = *(const u32x4*)q11;
  r.g11b = *(const u32x4*)(q11 + 8);
}

static __device__ __forceinline__ void blendB16(const Bld16& r, u32x4& o0, u32x4& o1) {
#pragma unroll
  for (int d = 0; d < 4; ++d) {
    float a0 = r.wv[0] * bflo(r.g00a[d]) + r.wv[1] * bflo(r.g01a[d]) +
               r.wv[2] * bflo(r.g10a[d]) + r.wv[3] * bflo(r.g11a[d]);
    float a1 = r.wv[0] * bfhi(r.g00a[d]) + r.wv[1] * bfhi(r.g01a[d]) +
               r.wv[2] * bfhi(r.g10a[d]) + r.wv[3] * bfhi(r.g11a[d]);
    o0[d] = packbf2(a0, a1);
    float b0 = r.wv[0] * bflo(r.g00b[d]) + r.wv[1] * bflo(r.g01b[d]) +
               r.wv[2] * bflo(r.g10b[d]) + r.wv[3] * bflo(r.g11b[d]);
    float b1 = r.wv[0] * bfhi(r.g00b[d]) + r.wv[1] * bfhi(r.g01b[d]) +
               r.wv[2] * bfhi(r.g10b[d]) + r.wv[3] * bfhi(r.g11b[d]);
    o1[d] = packbf2(b0, b1);
  }
}

__global__ __launch_bounds__(512) void k_gemm(const unsigned short* __restrict__ AW,
                                              const unsigned short* __restrict__ XH,
                                              const f32x4* __restrict__ W4,
                                              const unsigned* __restrict__ C4,
                                              float* __restrict__ out) {
  // double buffer: per buffer 48 KB = A [256][64 bf16] (32 KB) + B [128][64 bf16] (16 KB)
  __shared__ u32x4 lds2[2][3072];
  unsigned char* ldsbase = (unsigned char*)lds2;

  const int tid = threadIdx.x;
  const int bid = blockIdx.x;
  const int b = bid & 7;          // XCD swizzle: one batch per XCD (FETCH 186->15 MB)
  const int s0 = (bid >> 3) * 128;

  const int l = tid & 63;
  const int w = tid >> 6;
  const int wm = (w >> 1) * 64;  // 4 M-waves
  const int wn = (w & 1) * 64;   // 2 N-waves

  const int am = tid & 255;
  const int ah = tid >> 8;
  const unsigned short* arow = AW + am * KTOT + ah * 32;
  const unsigned swa = (unsigned)(am & 7) << 4;

  const int bn = tid >> 2;
  const int bc = (tid & 3) * 16;
  const int s = s0 + bn;
  const unsigned swb = (unsigned)(bn & 7) << 4;
  const unsigned short* xb = XH + b * (64 * 64 * 256);

  f32x4 acc[4][4];
#pragma unroll
  for (int i = 0; i < 4; ++i)
#pragma unroll
    for (int j = 0; j < 4; ++j) acc[i][j] = (f32x4){0.f, 0.f, 0.f, 0.f};

  u32x4 ar[4];
  u32x4 o0, o1;
  Bld16 bld;

  // prologue: tile 0 -> regs -> buffer 0
#pragma unroll
  for (int j = 0; j < 4; ++j) ar[j] = *(const u32x4*)(arow + j * 8);
  loadB16(xb, W4, C4, b, 0, 0, bc, s, bld);
  blendB16(bld, o0, o1);
  {
    unsigned char* ldsA = ldsbase;
    unsigned char* ldsB = ldsbase + 32768;
    const unsigned abase = (unsigned)am * 128u;
#pragma unroll
    for (int j = 0; j < 4; ++j)
      *(u32x4*)(ldsA + abase + (((unsigned)(ah * 64 + j * 16)) ^ swa)) = ar[j];
    const unsigned bbase = (unsigned)bn * 128u;
    *(u32x4*)(ldsB + bbase + (((unsigned)(bc * 2)) ^ swb)) = o0;
    *(u32x4*)(ldsB + bbase + (((unsigned)(bc * 2 + 16)) ^ swb)) = o1;
  }

  for (int ks = 0; ks < 36; ++ks) {
    const int cur = ks & 1;
    unsigned char* ldsA = ldsbase + cur * 49152;
    unsigned char* ldsB = ldsA + 32768;
    unsigned char* ldsAn = ldsbase + (cur ^ 1) * 49152;
    unsigned char* ldsBn = ldsAn + 32768;

    // issue next tile's global loads before the barrier (r5 placement: best measured)
    if (ks + 1 < 36) {
      int kn = (ks + 1) >> 2, cn = ((ks + 1) & 3) << 6;
#pragma unroll
      for (int j = 0; j < 4; ++j)
        ar[j] = *(const u32x4*)(arow + kn * 256 + cn + j * 8);
      loadB16(xb, W4, C4, b, kn, cn, bc, s, bld);
    }

    __syncthreads();  // buf[cur] writes visible; buf[cur^1] reads (iter ks-1) done

#pragma unroll
    for (int kk = 0; kk < 2; ++kk) {
      bf16x8 af[4], bfr[4];
      const unsigned co = (unsigned)(kk * 64 + ((l >> 4) * 16));
#pragma unroll
      for (int i = 0; i < 4; ++i) {
        int row = wm + i * 16 + (l & 15);
        af[i] = *(const bf16x8*)(ldsA + (unsigned)row * 128u +
                                 (co ^ ((unsigned)(row & 7) << 4)));
      }
#pragma unroll
      for (int j = 0; j < 4; ++j) {
        int col = wn + j * 16 + (l & 15);
        bfr[j] = *(const bf16x8*)(ldsB + (unsigned)col * 128u +
                                  (co ^ ((unsigned)(col & 7) << 4)));
      }
#pragma unroll
      for (int i = 0; i < 4; ++i)
#pragma unroll
        for (int j = 0; j < 4; ++j)
          acc[i][j] = __builtin_amdgcn_mfma_f32_16x16x32_bf16(af[i], bfr[j],
                                                              acc[i][j], 0, 0, 0);
    }

    // blend + write next tile into the other buffer (read side untouched)
    if (ks + 1 < 36) {
      blendB16(bld, o0, o1);
      const unsigned abase = (unsigned)am * 128u;
#pragma unroll
      for (int j = 0; j < 4; ++j)
        *(u32x4*)(ldsAn + abase + (((unsigned)(ah * 64 + j * 16)) ^ swa)) = ar[j];
      const unsigned bbase = (unsigned)bn * 128u;
      *(u32x4*)(ldsBn + bbase + (((unsigned)(bc * 2)) ^ swb)) = o0;
      *(u32x4*)(ldsBn + bbase + (((unsigned)(bc * 2 + 16)) ^ swb)) = o1;
    }
  }

  // epilogue: D layout col=lane&15, row=(lane>>4)*4+reg (m89)
  const int cn2 = l & 15;
  const int r0 = (l >> 4) * 4;
#pragma unroll
  for (int i = 0; i < 4; ++i) {
#pragma unroll
    for (int j = 0; j < 4; ++j) {
      int sc = s0 + wn + j * 16 + cn2;
#pragma unroll
      for (int r = 0; r < 4; ++r) {
        int o = wm + i * 16 + r0 + r;
        out[((b * 256 + o) << 12) + sc] = acc[i][j][r];
      }
    }
  }
}

extern "C" void kernel_launch(void* const* d_in, const int* in_sizes, int n_in,
                              void* d_out, int out_size, void* d_ws, size_t ws_size,
                              hipStream_t stream) {
  const float* x = (const float*)d_in[0];
  const float* wof = (const float*)d_in[1];
  const float* wc = (const float*)d_in[2];
  float* out = (float*)d_out;
  char* ws = (char*)d_ws;

  // ws layout (total 24.2 MB)
  unsigned short* XH = (unsigned short*)(ws);              // 16,777,216 B
  unsigned short* AW = (unsigned short*)(ws + 16777216);   //  1,179,648 B
  unsigned short* AOH = (unsigned short*)(ws + 17956864);  //    147,456 B
  unsigned short* AOL = (unsigned short*)(ws + 18104320);  //    147,456 B
  f32x4* W4 = (f32x4*)(ws + 18251776);                     //  4,718,592 B
  unsigned* C4 = (unsigned*)(ws + 22970368);               //  1,179,648 B (end 24,150,016)

  // d_out (33.5 MB) doubles as scratch before k_gemm overwrites it:
  //   [0, 16.8 MB)  : XL, bf16 residual of x (read by k_offc_mfma)
  //   [16.8, 30.9)  : 4 x 3 fp32 partial arrays from the channel-split offset conv
  unsigned short* XL = (unsigned short*)d_out;
  float* P0 = (float*)((char*)d_out + 16777216);

  k_nhwc<<<512, 256, 0, stream>>>(x, XH, XL);
  k_wprep<<<2304, 256, 0, stream>>>(wc, AW);
  k_wprep_off<<<288, 256, 0, stream>>>(wof, AOH, AOL);
  k_offc_mfma<<<2048, 256, 0, stream>>>(AOH, AOL, XH, XL, P0);
  k_xform3<<<1152, 256, 0, stream>>>(P0, W4, C4);
  k_gemm<<<256, 512, 0, stream>>>(AW, XH, W4, C4, out);
}

// Round 12
// 193.122 us; speedup vs baseline: 1.3464x; 1.1334x over previous
//
#include <hip/hip_runtime.h>
#include <hip/hip_bf16.h>

typedef float f32x4 __attribute__((ext_vector_type(4)));
typedef unsigned int u32x4 __attribute__((ext_vector_type(4)));
typedef __bf16 bf16x8 __attribute__((ext_vector_type(8)));

#define NSP 4096
#define KTOT 2304
#define PSTRIDE 294912  // 8*9*4096 floats per partial array

static __device__ __forceinline__ float bflo(unsigned u) {
  return __builtin_bit_cast(float, u << 16);
}
static __device__ __forceinline__ float bfhi(unsigned u) {
  return __builtin_bit_cast(float, u & 0xffff0000u);
}
static __device__ __forceinline__ unsigned short bfbits(float f) {
  return __builtin_bit_cast(unsigned short, (__bf16)f);
}
static __device__ __forceinline__ unsigned packbf2(float f0, float f1) {
  return (unsigned)bfbits(f0) | ((unsigned)bfbits(f1) << 16);
}
static __device__ __forceinline__ float bf16f(unsigned short h) {
  return __builtin_bit_cast(float, (unsigned)h << 16);
}

// ---------- x (B,C,H,W) f32 -> XH (B,H,W,C) bf16 ----------
__global__ __launch_bounds__(256) void k_nhwc(const float* __restrict__ x,
                                              unsigned short* __restrict__ XH) {
  const int by = blockIdx.x;            // b*64 + y
  const int t = threadIdx.x;
  const int xw = t & 63;
  const int cq = t >> 6;                // 0..3
  const float* xp = x + (((by >> 6) * 256 * 64 + (by & 63)) * 64 + xw);
  unsigned short* oh = XH + (by * 64 + xw) * 256;
#pragma unroll
  for (int j8 = 0; j8 < 8; ++j8) {
    const int c0 = cq * 64 + j8 * 8;
    u32x4 vh;
#pragma unroll
    for (int d = 0; d < 4; ++d) {
      float f0 = xp[(c0 + 2 * d) * 4096];
      float f1 = xp[(c0 + 2 * d + 1) * 4096];
      vh[d] = packbf2(f0, f1);
    }
    *(u32x4*)(oh + c0) = vh;
  }
}

// ---------- w_conv (Co,C,3,3) f32 -> AW (Co, k*256+c) bf16 ----------
__global__ void k_wprep(const float* __restrict__ wc, unsigned short* __restrict__ AW) {
  int idx = blockIdx.x * 256 + threadIdx.x;
  if (idx >= 256 * KTOT) return;
  int o = idx / KTOT;
  int r = idx - o * KTOT;
  int k = r >> 8, c = r & 255;
  AW[idx] = bfbits(wc[(o * 256 + c) * 9 + k]);
}

// ---------- w_offset (27,256,3,3) f32 -> AOH/AOL [32][tap*256+c] bf16 hi/lo ----------
__global__ void k_wprep_off(const float* __restrict__ wof,
                            unsigned short* __restrict__ AOH,
                            unsigned short* __restrict__ AOL) {
  int idx = blockIdx.x * 256 + threadIdx.x;   // 32*2304 = 73728
  if (idx >= 32 * KTOT) return;
  int m = idx / KTOT;
  int r = idx - m * KTOT;
  int t = r >> 8, c = r & 255;
  float v = (m < 27) ? wof[(m * 256 + c) * 9 + t] : 0.f;
  unsigned short h = bfbits(v);
  AOH[idx] = h;
  AOL[idx] = bfbits(v - bf16f(h));
}

// ---------- offset conv, (w_hi+w_lo)*x_bf16 MFMA, 4-way channel split ----------
// XL path dropped: working set per XCD now XH(2.1MB)+weights(0.3MB) < 4MB L2.
__global__ __launch_bounds__(256, 8) void k_offc_mfma(
    const unsigned short* __restrict__ AOH, const unsigned short* __restrict__ AOL,
    const unsigned short* __restrict__ XH, float* __restrict__ P0) {
  const int tid = threadIdx.x;
  const int l = tid & 63;
  const int w = tid >> 6;                 // 4 waves, each owns 16 cols
  const int bid = blockIdx.x;             // b(8) x y(64) x kh(4)
  const int b = bid & 7;                  // XCD swizzle: one batch per XCD
  const int y = (bid >> 3) & 63;
  const int kh = bid >> 9;                // channel quarter: kh*64 ..
  const int xcol = w * 16 + (l & 15);
  const int kq = kh * 64 + (l >> 4) * 8;
  const unsigned short* xb = XH + b * (64 * 64 * 256);
  const int mr = l & 15;

  f32x4 acc0 = (f32x4){0.f, 0.f, 0.f, 0.f};
  f32x4 acc1 = (f32x4){0.f, 0.f, 0.f, 0.f};

#pragma unroll
  for (int tap = 0; tap < 9; ++tap) {
    const int yy = y + tap / 3 - 1;
    const int xx = xcol + tap % 3 - 1;
    const bool valid = ((unsigned)yy < 64u) & ((unsigned)xx < 64u);
    const unsigned short* bp = xb + (yy * 64 + xx) * 256 + kq;
    const unsigned short* a0 = AOH + mr * KTOT + tap * 256 + kq;
    const unsigned short* a1 = AOH + (mr + 16) * KTOT + tap * 256 + kq;
    const unsigned short* c0p = AOL + mr * KTOT + tap * 256 + kq;
    const unsigned short* c1p = AOL + (mr + 16) * KTOT + tap * 256 + kq;
#pragma unroll
    for (int kc = 0; kc < 2; ++kc) {
      u32x4 zh = (u32x4){0u, 0u, 0u, 0u};
      u32x4 bhu = valid ? *(const u32x4*)(bp + kc * 32) : zh;
      bf16x8 bh = __builtin_bit_cast(bf16x8, bhu);
      bf16x8 ah0 = *(const bf16x8*)(a0 + kc * 32);
      bf16x8 ah1 = *(const bf16x8*)(a1 + kc * 32);
      bf16x8 al0 = *(const bf16x8*)(c0p + kc * 32);
      bf16x8 al1 = *(const bf16x8*)(c1p + kc * 32);
      acc0 = __builtin_amdgcn_mfma_f32_16x16x32_bf16(ah0, bh, acc0, 0, 0, 0);
      acc1 = __builtin_amdgcn_mfma_f32_16x16x32_bf16(ah1, bh, acc1, 0, 0, 0);
      acc0 = __builtin_amdgcn_mfma_f32_16x16x32_bf16(al0, bh, acc0, 0, 0, 0);
      acc1 = __builtin_amdgcn_mfma_f32_16x16x32_bf16(al1, bh, acc1, 0, 0, 0);
    }
  }

  // D layout: col=lane&15 (=our n), row=(lane>>4)*4+reg; plain store to partial[kh]
  const int s = y * 64 + xcol;
  float* Pk = P0 + kh * 3 * PSTRIDE;
#pragma unroll
  for (int mf = 0; mf < 2; ++mf) {
    f32x4 a = mf ? acc1 : acc0;
#pragma unroll
    for (int r = 0; r < 4; ++r) {
      int m = mf * 16 + (l >> 4) * 4 + r;
      if (m < 27) {
        int which = m / 9;
        int mm = m - which * 9;
        Pk[which * PSTRIDE + ((b * 9 + mm) << 12) + s] = a[r];
      }
    }
  }
}

// ---------- reduce 4 partials + base grid + sigmoid -> W4/C4 metadata ----------
__global__ void k_xform3(const float* __restrict__ P0, f32x4* __restrict__ W4,
                         unsigned* __restrict__ C4) {
  int idx = blockIdx.x * 256 + threadIdx.x;   // (b*9+k)*4096 + s
  if (idx >= 8 * 9 * NSP) return;
  int s = idx & 4095;
  int k = (idx >> 12) % 9;
  float oy = 0.f, ox = 0.f, lg = 0.f;
#pragma unroll
  for (int kh = 0; kh < 4; ++kh) {
    const float* Pk = P0 + kh * 3 * PSTRIDE;
    oy += Pk[idx];
    ox += Pk[PSTRIDE + idx];
    lg += Pk[2 * PSTRIDE + idx];
  }
  float py = oy + (float)(s >> 6) - 1.f + (float)(k / 3);
  float px = ox + (float)(s & 63) - 1.f + (float)(k % 3);
  float mk = 1.f / (1.f + __expf(-lg));

  float y0f = floorf(py), x0f = floorf(px);
  float ly = py - y0f, lx = px - x0f;
  int y0 = (int)y0f, x0 = (int)x0f;
  int y1 = y0 + 1, x1 = x0 + 1;
  float omy = 1.f - ly, omx = 1.f - lx;
  bool y0v = (unsigned)y0 < 64u, y1v = (unsigned)y1 < 64u;
  bool x0v = (unsigned)x0 < 64u, x1v = (unsigned)x1 < 64u;
  f32x4 wv;
  wv[0] = (y0v && x0v) ? omy * omx * mk : 0.f;
  wv[1] = (y0v && x1v) ? omy * lx * mk : 0.f;
  wv[2] = (y1v && x0v) ? ly * omx * mk : 0.f;
  wv[3] = (y1v && x1v) ? ly * lx * mk : 0.f;
  int y0c = min(max(y0, 0), 63), y1c = min(max(y1, 0), 63);
  int x0c = min(max(x0, 0), 63), x1c = min(max(x1, 0), 63);
  unsigned p00 = (unsigned)(y0c * 64 + x0c);
  unsigned p11 = (unsigned)(y1c * 64 + x1c);
  W4[idx] = wv;
  C4[idx] = p00 | (p11 << 16);
}

// ---------- fused sampling + implicit GEMM (r5 dbuf structure + W4/C4) ----------
struct Bld16 {
  u32x4 g00a, g00b, g01a, g01b, g10a, g10b, g11a, g11b;
  f32x4 wv;
};

static __device__ __forceinline__ void loadB16(const unsigned short* __restrict__ xb,
                                               const f32x4* __restrict__ W4,
                                               const unsigned* __restrict__ C4,
                                               int b, int k, int c0, int bc, int s,
                                               Bld16& r) {
  int ci = (b * 9 + k) * NSP + s;
  r.wv = W4[ci];
  unsigned c4 = C4[ci];
  unsigned p00 = c4 & 0xffffu, p11 = c4 >> 16;
  unsigned p01 = (p00 & ~63u) | (p11 & 63u);
  unsigned p10 = (p11 & ~63u) | (p00 & 63u);
  const unsigned short* base = xb + (c0 + bc);
  const unsigned short* q00 = base + (p00 << 8);
  const unsigned short* q01 = base + (p01 << 8);
  const unsigned short* q10 = base + (p10 << 8);
  const unsigned short* q11 = base + (p11 << 8);
  r.g00a = *(const u32x4*)q00;
  r.g00b = *(const u32x4*)(q00 + 8);
  r.g01a = *(const u32x4*)q01;
  r.g01b = *(const u32x4*)(q01 + 8);
  r.g10a = *(const u32x4*)q10;
  r.g10b = *(const u32x4*)(q10 + 8);
  r.g11a = *(const u32x4*)q11;
  r.g11b = *(const u32x4*)(q11 + 8);
}

static __device__ __forceinline__ void blendB16(const Bld16& r, u32x4& o0, u32x4& o1) {
#pragma unroll
  for (int d = 0; d < 4; ++d) {
    float a0 = r.wv[0] * bflo(r.g00a[d]) + r.wv[1] * bflo(r.g01a[d]) +
               r.wv[2] * bflo(r.g10a[d]) + r.wv[3] * bflo(r.g11a[d]);
    float a1 = r.wv[0] * bfhi(r.g00a[d]) + r.wv[1] * bfhi(r.g01a[d]) +
               r.wv[2] * bfhi(r.g10a[d]) + r.wv[3] * bfhi(r.g11a[d]);
    o0[d] = packbf2(a0, a1);
    float b0 = r.wv[0] * bflo(r.g00b[d]) + r.wv[1] * bflo(r.g01b[d]) +
               r.wv[2] * bflo(r.g10b[d]) + r.wv[3] * bflo(r.g11b[d]);
    float b1 = r.wv[0] * bfhi(r.g00b[d]) + r.wv[1] * bfhi(r.g01b[d]) +
               r.wv[2] * bfhi(r.g10b[d]) + r.wv[3] * bfhi(r.g11b[d]);
    o1[d] = packbf2(b0, b1);
  }
}

__global__ __launch_bounds__(512) void k_gemm(const unsigned short* __restrict__ AW,
                                              const unsigned short* __restrict__ XH,
                                              const f32x4* __restrict__ W4,
                                              const unsigned* __restrict__ C4,
                                              float* __restrict__ out) {
  // double buffer: per buffer 48 KB = A [256][64 bf16] (32 KB) + B [128][64 bf16] (16 KB)
  __shared__ u32x4 lds2[2][3072];
  unsigned char* ldsbase = (unsigned char*)lds2;

  const int tid = threadIdx.x;
  const int bid = blockIdx.x;
  const int b = bid & 7;          // XCD swizzle: one batch per XCD
  const int s0 = (bid >> 3) * 128;

  const int l = tid & 63;
  const int w = tid >> 6;
  const int wm = (w >> 1) * 64;  // 4 M-waves
  const int wn = (w & 1) * 64;   // 2 N-waves

  const int am = tid & 255;
  const int ah = tid >> 8;
  const unsigned short* arow = AW + am * KTOT + ah * 32;
  const unsigned swa = (unsigned)(am & 7) << 4;

  const int bn = tid >> 2;
  const int bc = (tid & 3) * 16;
  const int s = s0 + bn;
  const unsigned swb = (unsigned)(bn & 7) << 4;
  const unsigned short* xb = XH + b * (64 * 64 * 256);

  f32x4 acc[4][4];
#pragma unroll
  for (int i = 0; i < 4; ++i)
#pragma unroll
    for (int j = 0; j < 4; ++j) acc[i][j] = (f32x4){0.f, 0.f, 0.f, 0.f};

  u32x4 ar[4];
  u32x4 o0, o1;
  Bld16 bld;

  // prologue: tile 0 -> regs -> buffer 0
#pragma unroll
  for (int j = 0; j < 4; ++j) ar[j] = *(const u32x4*)(arow + j * 8);
  loadB16(xb, W4, C4, b, 0, 0, bc, s, bld);
  blendB16(bld, o0, o1);
  {
    unsigned char* ldsA = ldsbase;
    unsigned char* ldsB = ldsbase + 32768;
    const unsigned abase = (unsigned)am * 128u;
#pragma unroll
    for (int j = 0; j < 4; ++j)
      *(u32x4*)(ldsA + abase + (((unsigned)(ah * 64 + j * 16)) ^ swa)) = ar[j];
    const unsigned bbase = (unsigned)bn * 128u;
    *(u32x4*)(ldsB + bbase + (((unsigned)(bc * 2)) ^ swb)) = o0;
    *(u32x4*)(ldsB + bbase + (((unsigned)(bc * 2 + 16)) ^ swb)) = o1;
  }

  for (int ks = 0; ks < 36; ++ks) {
    const int cur = ks & 1;
    unsigned char* ldsA = ldsbase + cur * 49152;
    unsigned char* ldsB = ldsA + 32768;
    unsigned char* ldsAn = ldsbase + (cur ^ 1) * 49152;
    unsigned char* ldsBn = ldsAn + 32768;

    // issue next tile's global loads before the barrier (r5 placement: best measured)
    if (ks + 1 < 36) {
      int kn = (ks + 1) >> 2, cn = ((ks + 1) & 3) << 6;
#pragma unroll
      for (int j = 0; j < 4; ++j)
        ar[j] = *(const u32x4*)(arow + kn * 256 + cn + j * 8);
      loadB16(xb, W4, C4, b, kn, cn, bc, s, bld);
    }

    __syncthreads();  // buf[cur] writes visible; buf[cur^1] reads (iter ks-1) done

#pragma unroll
    for (int kk = 0; kk < 2; ++kk) {
      bf16x8 af[4], bfr[4];
      const unsigned co = (unsigned)(kk * 64 + ((l >> 4) * 16));
#pragma unroll
      for (int i = 0; i < 4; ++i) {
        int row = wm + i * 16 + (l & 15);
        af[i] = *(const bf16x8*)(ldsA + (unsigned)row * 128u +
                                 (co ^ ((unsigned)(row & 7) << 4)));
      }
#pragma unroll
      for (int j = 0; j < 4; ++j) {
        int col = wn + j * 16 + (l & 15);
        bfr[j] = *(const bf16x8*)(ldsB + (unsigned)col * 128u +
                                  (co ^ ((unsigned)(col & 7) << 4)));
      }
#pragma unroll
      for (int i = 0; i < 4; ++i)
#pragma unroll
        for (int j = 0; j < 4; ++j)
          acc[i][j] = __builtin_amdgcn_mfma_f32_16x16x32_bf16(af[i], bfr[j],
                                                              acc[i][j], 0, 0, 0);
    }

    // blend + write next tile into the other buffer (read side untouched)
    if (ks + 1 < 36) {
      blendB16(bld, o0, o1);
      const unsigned abase = (unsigned)am * 128u;
#pragma unroll
      for (int j = 0; j < 4; ++j)
        *(u32x4*)(ldsAn + abase + (((unsigned)(ah * 64 + j * 16)) ^ swa)) = ar[j];
      const unsigned bbase = (unsigned)bn * 128u;
      *(u32x4*)(ldsBn + bbase + (((unsigned)(bc * 2)) ^ swb)) = o0;
      *(u32x4*)(ldsBn + bbase + (((unsigned)(bc * 2 + 16)) ^ swb)) = o1;
    }
  }

  // epilogue: D layout col=lane&15, row=(lane>>4)*4+reg (m89)
  const int cn2 = l & 15;
  const int r0 = (l >> 4) * 4;
#pragma unroll
  for (int i = 0; i < 4; ++i) {
#pragma unroll
    for (int j = 0; j < 4; ++j) {
      int sc = s0 + wn + j * 16 + cn2;
#pragma unroll
      for (int r = 0; r < 4; ++r) {
        int o = wm + i * 16 + r0 + r;
        out[((b * 256 + o) << 12) + sc] = acc[i][j][r];
      }
    }
  }
}

extern "C" void kernel_launch(void* const* d_in, const int* in_sizes, int n_in,
                              void* d_out, int out_size, void* d_ws, size_t ws_size,
                              hipStream_t stream) {
  const float* x = (const float*)d_in[0];
  const float* wof = (const float*)d_in[1];
  const float* wc = (const float*)d_in[2];
  float* out = (float*)d_out;
  char* ws = (char*)d_ws;

  // ws layout (total 24.2 MB)
  unsigned short* XH = (unsigned short*)(ws);              // 16,777,216 B
  unsigned short* AW = (unsigned short*)(ws + 16777216);   //  1,179,648 B
  unsigned short* AOH = (unsigned short*)(ws + 17956864);  //    147,456 B
  unsigned short* AOL = (unsigned short*)(ws + 18104320);  //    147,456 B
  f32x4* W4 = (f32x4*)(ws + 18251776);                     //  4,718,592 B
  unsigned* C4 = (unsigned*)(ws + 22970368);               //  1,179,648 B (end 24,150,016)

  // d_out (33.5 MB) doubles as scratch before k_gemm overwrites it:
  //   [0, 14.2 MB) : 4 x 3 fp32 partial arrays from the channel-split offset conv
  float* P0 = (float*)d_out;

  k_nhwc<<<512, 256, 0, stream>>>(x, XH);
  k_wprep<<<2304, 256, 0, stream>>>(wc, AW);
  k_wprep_off<<<288, 256, 0, stream>>>(wof, AOH, AOL);
  k_offc_mfma<<<2048, 256, 0, stream>>>(AOH, AOL, XH, P0);
  k_xform3<<<1152, 256, 0, stream>>>(P0, W4, C4);
  k_gemm<<<256, 512, 0, stream>>>(AW, XH, W4, C4, out);
}

// Round 13
// 190.917 us; speedup vs baseline: 1.3619x; 1.0115x over previous
//
#include <hip/hip_runtime.h>
#include <hip/hip_bf16.h>

typedef float f32x4 __attribute__((ext_vector_type(4)));
typedef unsigned int u32x4 __attribute__((ext_vector_type(4)));
typedef __bf16 bf16x8 __attribute__((ext_vector_type(8)));

#define NSP 4096
#define KTOT 2304
#define PSTRIDE 294912  // 8*9*4096 floats per partial array

static __device__ __forceinline__ float bflo(unsigned u) {
  return __builtin_bit_cast(float, u << 16);
}
static __device__ __forceinline__ float bfhi(unsigned u) {
  return __builtin_bit_cast(float, u & 0xffff0000u);
}
static __device__ __forceinline__ unsigned short bfbits(float f) {
  return __builtin_bit_cast(unsigned short, (__bf16)f);
}
static __device__ __forceinline__ unsigned packbf2(float f0, float f1) {
  return (unsigned)bfbits(f0) | ((unsigned)bfbits(f1) << 16);
}
static __device__ __forceinline__ float bf16f(unsigned short h) {
  return __builtin_bit_cast(float, (unsigned)h << 16);
}

// ---------- x (B,C,H,W) f32 -> XH (B,H,W,C) bf16 ----------
__global__ __launch_bounds__(256) void k_nhwc(const float* __restrict__ x,
                                              unsigned short* __restrict__ XH) {
  const int by = blockIdx.x;            // b*64 + y
  const int t = threadIdx.x;
  const int xw = t & 63;
  const int cq = t >> 6;                // 0..3
  const float* xp = x + (((by >> 6) * 256 * 64 + (by & 63)) * 64 + xw);
  unsigned short* oh = XH + (by * 64 + xw) * 256;
#pragma unroll
  for (int j8 = 0; j8 < 8; ++j8) {
    const int c0 = cq * 64 + j8 * 8;
    u32x4 vh;
#pragma unroll
    for (int d = 0; d < 4; ++d) {
      float f0 = xp[(c0 + 2 * d) * 4096];
      float f1 = xp[(c0 + 2 * d + 1) * 4096];
      vh[d] = packbf2(f0, f1);
    }
    *(u32x4*)(oh + c0) = vh;
  }
}

// ---------- fused weight prep: AW (bf16) + AOH/AOL (bf16 hi/lo) ----------
__global__ void k_wprep_all(const float* __restrict__ wc, const float* __restrict__ wof,
                            unsigned short* __restrict__ AW,
                            unsigned short* __restrict__ AOH,
                            unsigned short* __restrict__ AOL) {
  int idx = blockIdx.x * 256 + threadIdx.x;
  if (idx < 256 * KTOT) {
    int o = idx / KTOT;
    int r = idx - o * KTOT;
    int k = r >> 8, c = r & 255;
    AW[idx] = bfbits(wc[(o * 256 + c) * 9 + k]);
  } else {
    int j = idx - 256 * KTOT;
    if (j < 32 * KTOT) {
      int m = j / KTOT;
      int r = j - m * KTOT;
      int t = r >> 8, c = r & 255;
      float v = (m < 27) ? wof[(m * 256 + c) * 9 + t] : 0.f;
      unsigned short h = bfbits(v);
      AOH[j] = h;
      AOL[j] = bfbits(v - bf16f(h));
    }
  }
}

// ---------- offset conv, (w_hi+w_lo)*x_bf16 MFMA, 4-way channel split ----------
__global__ __launch_bounds__(256, 8) void k_offc_mfma(
    const unsigned short* __restrict__ AOH, const unsigned short* __restrict__ AOL,
    const unsigned short* __restrict__ XH, float* __restrict__ P0) {
  const int tid = threadIdx.x;
  const int l = tid & 63;
  const int w = tid >> 6;                 // 4 waves, each owns 16 cols
  const int bid = blockIdx.x;             // b(8) x y(64) x kh(4)
  const int b = bid & 7;                  // XCD swizzle: one batch per XCD
  const int y = (bid >> 3) & 63;
  const int kh = bid >> 9;                // channel quarter: kh*64 ..
  const int xcol = w * 16 + (l & 15);
  const int kq = kh * 64 + (l >> 4) * 8;
  const unsigned short* xb = XH + b * (64 * 64 * 256);
  const int mr = l & 15;

  f32x4 acc0 = (f32x4){0.f, 0.f, 0.f, 0.f};
  f32x4 acc1 = (f32x4){0.f, 0.f, 0.f, 0.f};

#pragma unroll
  for (int tap = 0; tap < 9; ++tap) {
    const int yy = y + tap / 3 - 1;
    const int xx = xcol + tap % 3 - 1;
    const bool valid = ((unsigned)yy < 64u) & ((unsigned)xx < 64u);
    const unsigned short* bp = xb + (yy * 64 + xx) * 256 + kq;
    const unsigned short* a0 = AOH + mr * KTOT + tap * 256 + kq;
    const unsigned short* a1 = AOH + (mr + 16) * KTOT + tap * 256 + kq;
    const unsigned short* c0p = AOL + mr * KTOT + tap * 256 + kq;
    const unsigned short* c1p = AOL + (mr + 16) * KTOT + tap * 256 + kq;
#pragma unroll
    for (int kc = 0; kc < 2; ++kc) {
      u32x4 zh = (u32x4){0u, 0u, 0u, 0u};
      u32x4 bhu = valid ? *(const u32x4*)(bp + kc * 32) : zh;
      bf16x8 bh = __builtin_bit_cast(bf16x8, bhu);
      bf16x8 ah0 = *(const bf16x8*)(a0 + kc * 32);
      bf16x8 ah1 = *(const bf16x8*)(a1 + kc * 32);
      bf16x8 al0 = *(const bf16x8*)(c0p + kc * 32);
      bf16x8 al1 = *(const bf16x8*)(c1p + kc * 32);
      acc0 = __builtin_amdgcn_mfma_f32_16x16x32_bf16(ah0, bh, acc0, 0, 0, 0);
      acc1 = __builtin_amdgcn_mfma_f32_16x16x32_bf16(ah1, bh, acc1, 0, 0, 0);
      acc0 = __builtin_amdgcn_mfma_f32_16x16x32_bf16(al0, bh, acc0, 0, 0, 0);
      acc1 = __builtin_amdgcn_mfma_f32_16x16x32_bf16(al1, bh, acc1, 0, 0, 0);
    }
  }

  const int s = y * 64 + xcol;
  float* Pk = P0 + kh * 3 * PSTRIDE;
#pragma unroll
  for (int mf = 0; mf < 2; ++mf) {
    f32x4 a = mf ? acc1 : acc0;
#pragma unroll
    for (int r = 0; r < 4; ++r) {
      int m = mf * 16 + (l >> 4) * 4 + r;
      if (m < 27) {
        int which = m / 9;
        int mm = m - which * 9;
        Pk[which * PSTRIDE + ((b * 9 + mm) << 12) + s] = a[r];
      }
    }
  }
}

// ---------- reduce 4 partials + base grid + sigmoid -> W4/C4 metadata ----------
__global__ void k_xform3(const float* __restrict__ P0, f32x4* __restrict__ W4,
                         unsigned* __restrict__ C4) {
  int idx = blockIdx.x * 256 + threadIdx.x;   // (b*9+k)*4096 + s
  if (idx >= 8 * 9 * NSP) return;
  int s = idx & 4095;
  int k = (idx >> 12) % 9;
  float oy = 0.f, ox = 0.f, lg = 0.f;
#pragma unroll
  for (int kh = 0; kh < 4; ++kh) {
    const float* Pk = P0 + kh * 3 * PSTRIDE;
    oy += Pk[idx];
    ox += Pk[PSTRIDE + idx];
    lg += Pk[2 * PSTRIDE + idx];
  }
  float py = oy + (float)(s >> 6) - 1.f + (float)(k / 3);
  float px = ox + (float)(s & 63) - 1.f + (float)(k % 3);
  float mk = 1.f / (1.f + __expf(-lg));

  float y0f = floorf(py), x0f = floorf(px);
  float ly = py - y0f, lx = px - x0f;
  int y0 = (int)y0f, x0 = (int)x0f;
  int y1 = y0 + 1, x1 = x0 + 1;
  float omy = 1.f - ly, omx = 1.f - lx;
  bool y0v = (unsigned)y0 < 64u, y1v = (unsigned)y1 < 64u;
  bool x0v = (unsigned)x0 < 64u, x1v = (unsigned)x1 < 64u;
  f32x4 wv;
  wv[0] = (y0v && x0v) ? omy * omx * mk : 0.f;
  wv[1] = (y0v && x1v) ? omy * lx * mk : 0.f;
  wv[2] = (y1v && x0v) ? ly * omx * mk : 0.f;
  wv[3] = (y1v && x1v) ? ly * lx * mk : 0.f;
  int y0c = min(max(y0, 0), 63), y1c = min(max(y1, 0), 63);
  int x0c = min(max(x0, 0), 63), x1c = min(max(x1, 0), 63);
  unsigned p00 = (unsigned)(y0c * 64 + x0c);
  unsigned p11 = (unsigned)(y1c * 64 + x1c);
  W4[idx] = wv;
  C4[idx] = p00 | (p11 << 16);
}

// ---------- fused sampling + implicit GEMM (dbuf + phase-split schedule) ----------
struct Bld16 {
  u32x4 g00a, g00b, g01a, g01b, g10a, g10b, g11a, g11b;
  f32x4 wv;
};

static __device__ __forceinline__ void loadB16(const unsigned short* __restrict__ xb,
                                               const f32x4* __restrict__ W4,
                                               const unsigned* __restrict__ C4,
                                               int b, int k, int c0, int bc, int s,
                                               Bld16& r) {
  int ci = (b * 9 + k) * NSP + s;
  r.wv = W4[ci];
  unsigned c4 = C4[ci];
  unsigned p00 = c4 & 0xffffu, p11 = c4 >> 16;
  unsigned p01 = (p00 & ~63u) | (p11 & 63u);
  unsigned p10 = (p11 & ~63u) | (p00 & 63u);
  const unsigned short* base = xb + (c0 + bc);
  const unsigned short* q00 = base + (p00 << 8);
  const unsigned short* q01 = base + (p01 << 8);
  const unsigned short* q10 = base + (p10 << 8);
  const unsigned short* q11 = base + (p11 << 8);
  r.g00a = *(const u32x4*)q00;
  r.g00b = *(const u32x4*)(q00 + 8);
  r.g01a = *(const u32x4*)q01;
  r.g01b = *(const u32x4*)(q01 + 8);
  r.g10a = *(const u32x4*)q10;
  r.g10b = *(const u32x4*)(q10 + 8);
  r.g11a = *(const u32x4*)q11;
  r.g11b = *(const u32x4*)(q11 + 8);
}

static __device__ __forceinline__ void blendB16(const Bld16& r, u32x4& o0, u32x4& o1) {
#pragma unroll
  for (int d = 0; d < 4; ++d) {
    float a0 = r.wv[0] * bflo(r.g00a[d]) + r.wv[1] * bflo(r.g01a[d]) +
               r.wv[2] * bflo(r.g10a[d]) + r.wv[3] * bflo(r.g11a[d]);
    float a1 = r.wv[0] * bfhi(r.g00a[d]) + r.wv[1] * bfhi(r.g01a[d]) +
               r.wv[2] * bfhi(r.g10a[d]) + r.wv[3] * bfhi(r.g11a[d]);
    o0[d] = packbf2(a0, a1);
    float b0 = r.wv[0] * bflo(r.g00b[d]) + r.wv[1] * bflo(r.g01b[d]) +
               r.wv[2] * bflo(r.g10b[d]) + r.wv[3] * bflo(r.g11b[d]);
    float b1 = r.wv[0] * bfhi(r.g00b[d]) + r.wv[1] * bfhi(r.g01b[d]) +
               r.wv[2] * bfhi(r.g10b[d]) + r.wv[3] * bfhi(r.g11b[d]);
    o1[d] = packbf2(b0, b1);
  }
}

__global__ __launch_bounds__(512) void k_gemm(const unsigned short* __restrict__ AW,
                                              const unsigned short* __restrict__ XH,
                                              const f32x4* __restrict__ W4,
                                              const unsigned* __restrict__ C4,
                                              float* __restrict__ out) {
  // double buffer: per buffer 48 KB = A [256][64 bf16] (32 KB) + B [128][64 bf16] (16 KB)
  __shared__ u32x4 lds2[2][3072];
  unsigned char* ldsbase = (unsigned char*)lds2;

  const int tid = threadIdx.x;
  const int bid = blockIdx.x;
  const int b = bid & 7;          // XCD swizzle: one batch per XCD
  const int s0 = (bid >> 3) * 128;

  const int l = tid & 63;
  const int w = tid >> 6;
  const int wm = (w >> 1) * 64;  // 4 M-waves
  const int wn = (w & 1) * 64;   // 2 N-waves

  const int am = tid & 255;
  const int ah = tid >> 8;
  const unsigned short* arow = AW + am * KTOT + ah * 32;
  const unsigned swa = (unsigned)(am & 7) << 4;

  const int bn = tid >> 2;
  const int bc = (tid & 3) * 16;
  const int s = s0 + bn;
  const unsigned swb = (unsigned)(bn & 7) << 4;
  const unsigned short* xb = XH + b * (64 * 64 * 256);

  f32x4 acc[4][4];
#pragma unroll
  for (int i = 0; i < 4; ++i)
#pragma unroll
    for (int j = 0; j < 4; ++j) acc[i][j] = (f32x4){0.f, 0.f, 0.f, 0.f};

  u32x4 ar[4];
  u32x4 o0, o1;
  Bld16 bld;

  // prologue: tile 0 -> regs -> buffer 0
#pragma unroll
  for (int j = 0; j < 4; ++j) ar[j] = *(const u32x4*)(arow + j * 8);
  loadB16(xb, W4, C4, b, 0, 0, bc, s, bld);
  blendB16(bld, o0, o1);
  {
    unsigned char* ldsA = ldsbase;
    unsigned char* ldsB = ldsbase + 32768;
    const unsigned abase = (unsigned)am * 128u;
#pragma unroll
    for (int j = 0; j < 4; ++j)
      *(u32x4*)(ldsA + abase + (((unsigned)(ah * 64 + j * 16)) ^ swa)) = ar[j];
    const unsigned bbase = (unsigned)bn * 128u;
    *(u32x4*)(ldsB + bbase + (((unsigned)(bc * 2)) ^ swb)) = o0;
    *(u32x4*)(ldsB + bbase + (((unsigned)(bc * 2 + 16)) ^ swb)) = o1;
  }

  for (int ks = 0; ks < 36; ++ks) {
    const int cur = ks & 1;
    unsigned char* ldsA = ldsbase + cur * 49152;
    unsigned char* ldsB = ldsA + 32768;
    unsigned char* ldsAn = ldsbase + (cur ^ 1) * 49152;
    unsigned char* ldsBn = ldsAn + 32768;

    // LDS-only barrier: publish buf[cur] writes, retire buf[cur^1] reads.
    // Raw s_barrier + lgkmcnt(0) (ISA §8) — unlike __syncthreads this does NOT
    // force a vmcnt(0) drain, so global loads can stay in flight across it.
    asm volatile("s_waitcnt lgkmcnt(0)" ::: "memory");
    __builtin_amdgcn_s_barrier();

    const int kn = (ks + 1) >> 2, cn = ((ks + 1) & 3) << 6;

    // phase A: issue next tile's A-loads (latency hides under MFMA kk=0)
    if (ks + 1 < 36) {
#pragma unroll
      for (int j = 0; j < 4; ++j)
        ar[j] = *(const u32x4*)(arow + kn * 256 + cn + j * 8);
    }

    // MFMA half 1 (kk=0)
    __builtin_amdgcn_s_setprio(1);
    {
      bf16x8 af[4], bfr[4];
      const unsigned co = (unsigned)((l >> 4) * 16);
#pragma unroll
      for (int i = 0; i < 4; ++i) {
        int row = wm + i * 16 + (l & 15);
        af[i] = *(const bf16x8*)(ldsA + (unsigned)row * 128u +
                                 (co ^ ((unsigned)(row & 7) << 4)));
      }
#pragma unroll
      for (int j = 0; j < 4; ++j) {
        int col = wn + j * 16 + (l & 15);
        bfr[j] = *(const bf16x8*)(ldsB + (unsigned)col * 128u +
                                  (co ^ ((unsigned)(col & 7) << 4)));
      }
#pragma unroll
      for (int i = 0; i < 4; ++i)
#pragma unroll
        for (int j = 0; j < 4; ++j)
          acc[i][j] = __builtin_amdgcn_mfma_f32_16x16x32_bf16(af[i], bfr[j],
                                                              acc[i][j], 0, 0, 0);
    }
    __builtin_amdgcn_s_setprio(0);

    // phase B: issue next tile's gathers (latency hides under MFMA kk=1)
    if (ks + 1 < 36) loadB16(xb, W4, C4, b, kn, cn, bc, s, bld);

    // MFMA half 2 (kk=1)
    __builtin_amdgcn_s_setprio(1);
    {
      bf16x8 af[4], bfr[4];
      const unsigned co = (unsigned)(64 + (l >> 4) * 16);
#pragma unroll
      for (int i = 0; i < 4; ++i) {
        int row = wm + i * 16 + (l & 15);
        af[i] = *(const bf16x8*)(ldsA + (unsigned)row * 128u +
                                 (co ^ ((unsigned)(row & 7) << 4)));
      }
#pragma unroll
      for (int j = 0; j < 4; ++j) {
        int col = wn + j * 16 + (l & 15);
        bfr[j] = *(const bf16x8*)(ldsB + (unsigned)col * 128u +
                                  (co ^ ((unsigned)(col & 7) << 4)));
      }
#pragma unroll
      for (int i = 0; i < 4; ++i)
#pragma unroll
        for (int j = 0; j < 4; ++j)
          acc[i][j] = __builtin_amdgcn_mfma_f32_16x16x32_bf16(af[i], bfr[j],
                                                              acc[i][j], 0, 0, 0);
    }
    __builtin_amdgcn_s_setprio(0);

    // phase C: blend + stage next tile into the other buffer
    if (ks + 1 < 36) {
      blendB16(bld, o0, o1);
      const unsigned abase = (unsigned)am * 128u;
#pragma unroll
      for (int j = 0; j < 4; ++j)
        *(u32x4*)(ldsAn + abase + (((unsigned)(ah * 64 + j * 16)) ^ swa)) = ar[j];
      const unsigned bbase = (unsigned)bn * 128u;
      *(u32x4*)(ldsBn + bbase + (((unsigned)(bc * 2)) ^ swb)) = o0;
      *(u32x4*)(ldsBn + bbase + (((unsigned)(bc * 2 + 16)) ^ swb)) = o1;
    }
  }

  // epilogue: D layout col=lane&15, row=(lane>>4)*4+reg (m89)
  const int cn2 = l & 15;
  const int r0 = (l >> 4) * 4;
#pragma unroll
  for (int i = 0; i < 4; ++i) {
#pragma unroll
    for (int j = 0; j < 4; ++j) {
      int sc = s0 + wn + j * 16 + cn2;
#pragma unroll
      for (int r = 0; r < 4; ++r) {
        int o = wm + i * 16 + r0 + r;
        out[((b * 256 + o) << 12) + sc] = acc[i][j][r];
      }
    }
  }
}

extern "C" void kernel_launch(void* const* d_in, const int* in_sizes, int n_in,
                              void* d_out, int out_size, void* d_ws, size_t ws_size,
                              hipStream_t stream) {
  const float* x = (const float*)d_in[0];
  const float* wof = (const float*)d_in[1];
  const float* wc = (const float*)d_in[2];
  float* out = (float*)d_out;
  char* ws = (char*)d_ws;

  // ws layout (total 24.2 MB)
  unsigned short* XH = (unsigned short*)(ws);              // 16,777,216 B
  unsigned short* AW = (unsigned short*)(ws + 16777216);   //  1,179,648 B
  unsigned short* AOH = (unsigned short*)(ws + 17956864);  //    147,456 B
  unsigned short* AOL = (unsigned short*)(ws + 18104320);  //    147,456 B
  f32x4* W4 = (f32x4*)(ws + 18251776);                     //  4,718,592 B
  unsigned* C4 = (unsigned*)(ws + 22970368);               //  1,179,648 B (end 24,150,016)

  // d_out doubles as scratch before k_gemm overwrites it:
  //   [0, 14.2 MB) : 4 x 3 fp32 partial arrays from the channel-split offset conv
  float* P0 = (float*)d_out;

  k_nhwc<<<512, 256, 0, stream>>>(x, XH);
  k_wprep_all<<<2592, 256, 0, stream>>>(wc, wof, AW, AOH, AOL);
  k_offc_mfma<<<2048, 256, 0, stream>>>(AOH, AOL, XH, P0);
  k_xform3<<<1152, 256, 0, stream>>>(P0, W4, C4);
  k_gemm<<<256, 512, 0, stream>>>(AW, XH, W4, C4, out);
}

// Round 14
// 177.808 us; speedup vs baseline: 1.4623x; 1.0737x over previous
//
#include <hip/hip_runtime.h>
#include <hip/hip_bf16.h>

typedef float f32x4 __attribute__((ext_vector_type(4)));
typedef unsigned int u32x4 __attribute__((ext_vector_type(4)));
typedef __bf16 bf16x8 __attribute__((ext_vector_type(8)));

#define NSP 4096
#define KTOT 2304

static __device__ __forceinline__ float bflo(unsigned u) {
  return __builtin_bit_cast(float, u << 16);
}
static __device__ __forceinline__ float bfhi(unsigned u) {
  return __builtin_bit_cast(float, u & 0xffff0000u);
}
static __device__ __forceinline__ unsigned short bfbits(float f) {
  return __builtin_bit_cast(unsigned short, (__bf16)f);
}
static __device__ __forceinline__ unsigned packbf2(float f0, float f1) {
  return (unsigned)bfbits(f0) | ((unsigned)bfbits(f1) << 16);
}
static __device__ __forceinline__ float bf16f(unsigned short h) {
  return __builtin_bit_cast(float, (unsigned)h << 16);
}

// ---------- x (B,C,H,W) f32 -> XH (B,H,W,C) bf16 ----------
__global__ __launch_bounds__(256) void k_nhwc(const float* __restrict__ x,
                                              unsigned short* __restrict__ XH) {
  const int by = blockIdx.x;            // b*64 + y
  const int t = threadIdx.x;
  const int xw = t & 63;
  const int cq = t >> 6;                // 0..3
  const float* xp = x + (((by >> 6) * 256 * 64 + (by & 63)) * 64 + xw);
  unsigned short* oh = XH + (by * 64 + xw) * 256;
#pragma unroll
  for (int j8 = 0; j8 < 8; ++j8) {
    const int c0 = cq * 64 + j8 * 8;
    u32x4 vh;
#pragma unroll
    for (int d = 0; d < 4; ++d) {
      float f0 = xp[(c0 + 2 * d) * 4096];
      float f1 = xp[(c0 + 2 * d + 1) * 4096];
      vh[d] = packbf2(f0, f1);
    }
    *(u32x4*)(oh + c0) = vh;
  }
}

// ---------- fused weight prep: AW (bf16) + AOH/AOL (bf16 hi/lo) ----------
__global__ void k_wprep_all(const float* __restrict__ wc, const float* __restrict__ wof,
                            unsigned short* __restrict__ AW,
                            unsigned short* __restrict__ AOH,
                            unsigned short* __restrict__ AOL) {
  int idx = blockIdx.x * 256 + threadIdx.x;
  if (idx < 256 * KTOT) {
    int o = idx / KTOT;
    int r = idx - o * KTOT;
    int k = r >> 8, c = r & 255;
    AW[idx] = bfbits(wc[(o * 256 + c) * 9 + k]);
  } else {
    int j = idx - 256 * KTOT;
    if (j < 32 * KTOT) {
      int m = j / KTOT;
      int r = j - m * KTOT;
      int t = r >> 8, c = r & 255;
      float v = (m < 27) ? wof[(m * 256 + c) * 9 + t] : 0.f;
      unsigned short h = bfbits(v);
      AOH[j] = h;
      AOL[j] = bfbits(v - bf16f(h));
    }
  }
}

// ---------- offset conv as LDS-staged implicit GEMM + fused xform ----------
// M=32 (27 used), N=64 px (one y-row), K = 9 taps x 256 ch (hi+lo A).
// B-stage: coalesced shifted-row reads of XH into 8 KB LDS, XOR-swizzled
// (same write/read pattern as k_gemm's B tile — measured 0 conflicts).
__global__ __launch_bounds__(256) void k_offc2(const unsigned short* __restrict__ AOH,
                                               const unsigned short* __restrict__ AOL,
                                               const unsigned short* __restrict__ XH,
                                               f32x4* __restrict__ W4,
                                               unsigned* __restrict__ C4) {
  __shared__ u32x4 ldsq[512];   // 8 KB: B-tile [64 px][64 ch] bf16, then acc f32 [32][64]
  unsigned char* ldsB = (unsigned char*)ldsq;
  float* lds32 = (float*)ldsq;

  const int tid = threadIdx.x;
  const int bid = blockIdx.x;            // y(64) x b(8)
  const int b = bid & 7;                 // XCD swizzle: one batch per XCD
  const int y = bid >> 3;
  const int l = tid & 63;
  const int w = tid >> 6;                // 4 waves, wave owns px [w*16, w*16+16)

  const unsigned short* xb = XH + b * (64 * 64 * 256);
  const int mr = l & 15;
  const int ko = (l >> 4) * 8;           // element offset within K=32 fragment

  // B staging: thread t covers px = t>>2, 16-ch quarter qtr = t&3 (32 B)
  const int sp = tid >> 2;
  const int qtr = tid & 3;
  const unsigned swb = (unsigned)(sp & 7) << 4;

  f32x4 acc0 = (f32x4){0.f, 0.f, 0.f, 0.f};   // m rows 0-15
  f32x4 acc1 = (f32x4){0.f, 0.f, 0.f, 0.f};   // m rows 16-31

  for (int ks = 0; ks < 36; ++ks) {
    const int tap = ks >> 2, q = ks & 3;

    // coalesced shifted-row load (wave = contiguous 4 KB, modulo borders)
    const int yy = y + tap / 3 - 1;
    const int xx = sp + tap % 3 - 1;
    const bool valid = ((unsigned)yy < 64u) & ((unsigned)xx < 64u);
    const int yyc = min(max(yy, 0), 63), xxc = min(max(xx, 0), 63);
    const unsigned short* src = xb + ((yyc * 64 + xxc) * 256 + q * 64 + qtr * 16);
    u32x4 z = (u32x4){0u, 0u, 0u, 0u};
    u32x4 v0 = valid ? *(const u32x4*)src : z;
    u32x4 v1 = valid ? *(const u32x4*)(src + 8) : z;

    __syncthreads();  // previous step's MFMA LDS reads done
    *(u32x4*)(ldsB + (unsigned)sp * 128u + (((unsigned)(qtr * 32)) ^ swb)) = v0;
    *(u32x4*)(ldsB + (unsigned)sp * 128u + (((unsigned)(qtr * 32 + 16)) ^ swb)) = v1;
    __syncthreads();

    const unsigned short* abase = AOH + mr * KTOT + tap * 256 + q * 64 + ko;
    const unsigned short* cbase = AOL + mr * KTOT + tap * 256 + q * 64 + ko;
#pragma unroll
    for (int kc = 0; kc < 2; ++kc) {
      bf16x8 ah0 = *(const bf16x8*)(abase + kc * 32);
      bf16x8 ah1 = *(const bf16x8*)(abase + 16 * KTOT + kc * 32);
      bf16x8 al0 = *(const bf16x8*)(cbase + kc * 32);
      bf16x8 al1 = *(const bf16x8*)(cbase + 16 * KTOT + kc * 32);
      int col = w * 16 + (l & 15);
      bf16x8 bh = *(const bf16x8*)(ldsB + (unsigned)col * 128u +
                                   (((unsigned)(kc * 64 + (l >> 4) * 16)) ^
                                    ((unsigned)(col & 7) << 4)));
      acc0 = __builtin_amdgcn_mfma_f32_16x16x32_bf16(ah0, bh, acc0, 0, 0, 0);
      acc1 = __builtin_amdgcn_mfma_f32_16x16x32_bf16(ah1, bh, acc1, 0, 0, 0);
      acc0 = __builtin_amdgcn_mfma_f32_16x16x32_bf16(al0, bh, acc0, 0, 0, 0);
      acc1 = __builtin_amdgcn_mfma_f32_16x16x32_bf16(al1, bh, acc1, 0, 0, 0);
    }
  }

  // stage acc -> lds32 [32 m][64 px]  (D layout: col=lane&15, row=(l>>4)*4+reg)
  __syncthreads();
#pragma unroll
  for (int mf = 0; mf < 2; ++mf) {
    f32x4 a = mf ? acc1 : acc0;
#pragma unroll
    for (int r = 0; r < 4; ++r) {
      int m = mf * 16 + (l >> 4) * 4 + r;
      int px = w * 16 + (l & 15);
      lds32[m * 64 + px] = a[r];
    }
  }
  __syncthreads();

  // fused xform: per (k, px) compute bilinear weights + packed corner indices
#pragma unroll
  for (int it = 0; it < 3; ++it) {
    int idx = tid + it * 256;
    if (idx < 9 * 64) {
      int k = idx >> 6, px = idx & 63;
      float oy = lds32[k * 64 + px];
      float ox = lds32[(9 + k) * 64 + px];
      float lg = lds32[(18 + k) * 64 + px];
      int s = y * 64 + px;
      float py = oy + (float)y - 1.f + (float)(k / 3);
      float pxf = ox + (float)px - 1.f + (float)(k % 3);
      float mk = 1.f / (1.f + __expf(-lg));

      float y0f = floorf(py), x0f = floorf(pxf);
      float ly = py - y0f, lx = pxf - x0f;
      int y0 = (int)y0f, x0 = (int)x0f;
      int y1 = y0 + 1, x1 = x0 + 1;
      float omy = 1.f - ly, omx = 1.f - lx;
      bool y0v = (unsigned)y0 < 64u, y1v = (unsigned)y1 < 64u;
      bool x0v = (unsigned)x0 < 64u, x1v = (unsigned)x1 < 64u;
      f32x4 wv;
      wv[0] = (y0v && x0v) ? omy * omx * mk : 0.f;
      wv[1] = (y0v && x1v) ? omy * lx * mk : 0.f;
      wv[2] = (y1v && x0v) ? ly * omx * mk : 0.f;
      wv[3] = (y1v && x1v) ? ly * lx * mk : 0.f;
      int y0c = min(max(y0, 0), 63), y1c = min(max(y1, 0), 63);
      int x0c = min(max(x0, 0), 63), x1c = min(max(x1, 0), 63);
      unsigned p00 = (unsigned)(y0c * 64 + x0c);
      unsigned p11 = (unsigned)(y1c * 64 + x1c);
      int ci = (b * 9 + k) * NSP + s;
      W4[ci] = wv;
      C4[ci] = p00 | (p11 << 16);
    }
  }
}

// ---------- fused sampling + implicit GEMM (dbuf + phase-split schedule) ----------
struct Bld16 {
  u32x4 g00a, g00b, g01a, g01b, g10a, g10b, g11a, g11b;
  f32x4 wv;
};

static __device__ __forceinline__ void loadB16(const unsigned short* __restrict__ xb,
                                               const f32x4* __restrict__ W4,
                                               const unsigned* __restrict__ C4,
                                               int b, int k, int c0, int bc, int s,
                                               Bld16& r) {
  int ci = (b * 9 + k) * NSP + s;
  r.wv = W4[ci];
  unsigned c4 = C4[ci];
  unsigned p00 = c4 & 0xffffu, p11 = c4 >> 16;
  unsigned p01 = (p00 & ~63u) | (p11 & 63u);
  unsigned p10 = (p11 & ~63u) | (p00 & 63u);
  const unsigned short* base = xb + (c0 + bc);
  const unsigned short* q00 = base + (p00 << 8);
  const unsigned short* q01 = base + (p01 << 8);
  const unsigned short* q10 = base + (p10 << 8);
  const unsigned short* q11 = base + (p11 << 8);
  r.g00a = *(const u32x4*)q00;
  r.g00b = *(const u32x4*)(q00 + 8);
  r.g01a = *(const u32x4*)q01;
  r.g01b = *(const u32x4*)(q01 + 8);
  r.g10a = *(const u32x4*)q10;
  r.g10b = *(const u32x4*)(q10 + 8);
  r.g11a = *(const u32x4*)q11;
  r.g11b = *(const u32x4*)(q11 + 8);
}

static __device__ __forceinline__ void blendB16(const Bld16& r, u32x4& o0, u32x4& o1) {
#pragma unroll
  for (int d = 0; d < 4; ++d) {
    float a0 = r.wv[0] * bflo(r.g00a[d]) + r.wv[1] * bflo(r.g01a[d]) +
               r.wv[2] * bflo(r.g10a[d]) + r.wv[3] * bflo(r.g11a[d]);
    float a1 = r.wv[0] * bfhi(r.g00a[d]) + r.wv[1] * bfhi(r.g01a[d]) +
               r.wv[2] * bfhi(r.g10a[d]) + r.wv[3] * bfhi(r.g11a[d]);
    o0[d] = packbf2(a0, a1);
    float b0 = r.wv[0] * bflo(r.g00b[d]) + r.wv[1] * bflo(r.g01b[d]) +
               r.wv[2] * bflo(r.g10b[d]) + r.wv[3] * bflo(r.g11b[d]);
    float b1 = r.wv[0] * bfhi(r.g00b[d]) + r.wv[1] * bfhi(r.g01b[d]) +
               r.wv[2] * bfhi(r.g10b[d]) + r.wv[3] * bfhi(r.g11b[d]);
    o1[d] = packbf2(b0, b1);
  }
}

__global__ __launch_bounds__(512) void k_gemm(const unsigned short* __restrict__ AW,
                                              const unsigned short* __restrict__ XH,
                                              const f32x4* __restrict__ W4,
                                              const unsigned* __restrict__ C4,
                                              float* __restrict__ out) {
  // double buffer: per buffer 48 KB = A [256][64 bf16] (32 KB) + B [128][64 bf16] (16 KB)
  __shared__ u32x4 lds2[2][3072];
  unsigned char* ldsbase = (unsigned char*)lds2;

  const int tid = threadIdx.x;
  const int bid = blockIdx.x;
  const int b = bid & 7;          // XCD swizzle: one batch per XCD
  const int s0 = (bid >> 3) * 128;

  const int l = tid & 63;
  const int w = tid >> 6;
  const int wm = (w >> 1) * 64;  // 4 M-waves
  const int wn = (w & 1) * 64;   // 2 N-waves

  const int am = tid & 255;
  const int ah = tid >> 8;
  const unsigned short* arow = AW + am * KTOT + ah * 32;
  const unsigned swa = (unsigned)(am & 7) << 4;

  const int bn = tid >> 2;
  const int bc = (tid & 3) * 16;
  const int s = s0 + bn;
  const unsigned swb = (unsigned)(bn & 7) << 4;
  const unsigned short* xb = XH + b * (64 * 64 * 256);

  f32x4 acc[4][4];
#pragma unroll
  for (int i = 0; i < 4; ++i)
#pragma unroll
    for (int j = 0; j < 4; ++j) acc[i][j] = (f32x4){0.f, 0.f, 0.f, 0.f};

  u32x4 ar[4];
  u32x4 o0, o1;
  Bld16 bld;

  // prologue: tile 0 -> regs -> buffer 0
#pragma unroll
  for (int j = 0; j < 4; ++j) ar[j] = *(const u32x4*)(arow + j * 8);
  loadB16(xb, W4, C4, b, 0, 0, bc, s, bld);
  blendB16(bld, o0, o1);
  {
    unsigned char* ldsA = ldsbase;
    unsigned char* ldsB = ldsbase + 32768;
    const unsigned abase = (unsigned)am * 128u;
#pragma unroll
    for (int j = 0; j < 4; ++j)
      *(u32x4*)(ldsA + abase + (((unsigned)(ah * 64 + j * 16)) ^ swa)) = ar[j];
    const unsigned bbase = (unsigned)bn * 128u;
    *(u32x4*)(ldsB + bbase + (((unsigned)(bc * 2)) ^ swb)) = o0;
    *(u32x4*)(ldsB + bbase + (((unsigned)(bc * 2 + 16)) ^ swb)) = o1;
  }

  for (int ks = 0; ks < 36; ++ks) {
    const int cur = ks & 1;
    unsigned char* ldsA = ldsbase + cur * 49152;
    unsigned char* ldsB = ldsA + 32768;
    unsigned char* ldsAn = ldsbase + (cur ^ 1) * 49152;
    unsigned char* ldsBn = ldsAn + 32768;

    // LDS-only barrier (no vmcnt drain): publish buf[cur], retire buf[cur^1] reads
    asm volatile("s_waitcnt lgkmcnt(0)" ::: "memory");
    __builtin_amdgcn_s_barrier();

    const int kn = (ks + 1) >> 2, cn = ((ks + 1) & 3) << 6;

    // phase A: issue next tile's A-loads (latency hides under MFMA kk=0)
    if (ks + 1 < 36) {
#pragma unroll
      for (int j = 0; j < 4; ++j)
        ar[j] = *(const u32x4*)(arow + kn * 256 + cn + j * 8);
    }

    // MFMA half 1 (kk=0)
    __builtin_amdgcn_s_setprio(1);
    {
      bf16x8 af[4], bfr[4];
      const unsigned co = (unsigned)((l >> 4) * 16);
#pragma unroll
      for (int i = 0; i < 4; ++i) {
        int row = wm + i * 16 + (l & 15);
        af[i] = *(const bf16x8*)(ldsA + (unsigned)row * 128u +
                                 (co ^ ((unsigned)(row & 7) << 4)));
      }
#pragma unroll
      for (int j = 0; j < 4; ++j) {
        int col = wn + j * 16 + (l & 15);
        bfr[j] = *(const bf16x8*)(ldsB + (unsigned)col * 128u +
                                  (co ^ ((unsigned)(col & 7) << 4)));
      }
#pragma unroll
      for (int i = 0; i < 4; ++i)
#pragma unroll
        for (int j = 0; j < 4; ++j)
          acc[i][j] = __builtin_amdgcn_mfma_f32_16x16x32_bf16(af[i], bfr[j],
                                                              acc[i][j], 0, 0, 0);
    }
    __builtin_amdgcn_s_setprio(0);

    // phase B: issue next tile's gathers (latency hides under MFMA kk=1)
    if (ks + 1 < 36) loadB16(xb, W4, C4, b, kn, cn, bc, s, bld);

    // MFMA half 2 (kk=1)
    __builtin_amdgcn_s_setprio(1);
    {
      bf16x8 af[4], bfr[4];
      const unsigned co = (unsigned)(64 + (l >> 4) * 16);
#pragma unroll
      for (int i = 0; i < 4; ++i) {
        int row = wm + i * 16 + (l & 15);
        af[i] = *(const bf16x8*)(ldsA + (unsigned)row * 128u +
                                 (co ^ ((unsigned)(row & 7) << 4)));
      }
#pragma unroll
      for (int j = 0; j < 4; ++j) {
        int col = wn + j * 16 + (l & 15);
        bfr[j] = *(const bf16x8*)(ldsB + (unsigned)col * 128u +
                                  (co ^ ((unsigned)(col & 7) << 4)));
      }
#pragma unroll
      for (int i = 0; i < 4; ++i)
#pragma unroll
        for (int j = 0; j < 4; ++j)
          acc[i][j] = __builtin_amdgcn_mfma_f32_16x16x32_bf16(af[i], bfr[j],
                                                              acc[i][j], 0, 0, 0);
    }
    __builtin_amdgcn_s_setprio(0);

    // phase C: blend + stage next tile into the other buffer
    if (ks + 1 < 36) {
      blendB16(bld, o0, o1);
      const unsigned abase = (unsigned)am * 128u;
#pragma unroll
      for (int j = 0; j < 4; ++j)
        *(u32x4*)(ldsAn + abase + (((unsigned)(ah * 64 + j * 16)) ^ swa)) = ar[j];
      const unsigned bbase = (unsigned)bn * 128u;
      *(u32x4*)(ldsBn + bbase + (((unsigned)(bc * 2)) ^ swb)) = o0;
      *(u32x4*)(ldsBn + bbase + (((unsigned)(bc * 2 + 16)) ^ swb)) = o1;
    }
  }

  // epilogue: D layout col=lane&15, row=(lane>>4)*4+reg (m89)
  const int cn2 = l & 15;
  const int r0 = (l >> 4) * 4;
#pragma unroll
  for (int i = 0; i < 4; ++i) {
#pragma unroll
    for (int j = 0; j < 4; ++j) {
      int sc = s0 + wn + j * 16 + cn2;
#pragma unroll
      for (int r = 0; r < 4; ++r) {
        int o = wm + i * 16 + r0 + r;
        out[((b * 256 + o) << 12) + sc] = acc[i][j][r];
      }
    }
  }
}

extern "C" void kernel_launch(void* const* d_in, const int* in_sizes, int n_in,
                              void* d_out, int out_size, void* d_ws, size_t ws_size,
                              hipStream_t stream) {
  const float* x = (const float*)d_in[0];
  const float* wof = (const float*)d_in[1];
  const float* wc = (const float*)d_in[2];
  float* out = (float*)d_out;
  char* ws = (char*)d_ws;

  // ws layout (total 24.2 MB)
  unsigned short* XH = (unsigned short*)(ws);              // 16,777,216 B
  unsigned short* AW = (unsigned short*)(ws + 16777216);   //  1,179,648 B
  unsigned short* AOH = (unsigned short*)(ws + 17956864);  //    147,456 B
  unsigned short* AOL = (unsigned short*)(ws + 18104320);  //    147,456 B
  f32x4* W4 = (f32x4*)(ws + 18251776);                     //  4,718,592 B
  unsigned* C4 = (unsigned*)(ws + 22970368);               //  1,179,648 B (end 24,150,016)

  k_nhwc<<<512, 256, 0, stream>>>(x, XH);
  k_wprep_all<<<2592, 256, 0, stream>>>(wc, wof, AW, AOH, AOL);
  k_offc2<<<512, 256, 0, stream>>>(AOH, AOL, XH, W4, C4);
  k_gemm<<<256, 512, 0, stream>>>(AW, XH, W4, C4, out);
}

// Round 15
// 126.534 us; speedup vs baseline: 2.0549x; 1.4052x over previous
//
#include <hip/hip_runtime.h>
#include <hip/hip_bf16.h>

typedef float f32x4 __attribute__((ext_vector_type(4)));
typedef unsigned int u32x4 __attribute__((ext_vector_type(4)));
typedef __bf16 bf16x8 __attribute__((ext_vector_type(8)));

#define NSP 4096
#define KTOT 2304

static __device__ __forceinline__ float bflo(unsigned u) {
  return __builtin_bit_cast(float, u << 16);
}
static __device__ __forceinline__ float bfhi(unsigned u) {
  return __builtin_bit_cast(float, u & 0xffff0000u);
}
static __device__ __forceinline__ unsigned short bfbits(float f) {
  return __builtin_bit_cast(unsigned short, (__bf16)f);
}
static __device__ __forceinline__ unsigned packbf2(float f0, float f1) {
  return (unsigned)bfbits(f0) | ((unsigned)bfbits(f1) << 16);
}
static __device__ __forceinline__ float bf16f(unsigned short h) {
  return __builtin_bit_cast(float, (unsigned)h << 16);
}

// ---------- x (B,C,H,W) f32 -> XH (B,H,W,C) bf16 ----------
__global__ __launch_bounds__(256) void k_nhwc(const float* __restrict__ x,
                                              unsigned short* __restrict__ XH) {
  const int by = blockIdx.x;            // b*64 + y
  const int t = threadIdx.x;
  const int xw = t & 63;
  const int cq = t >> 6;                // 0..3
  const float* xp = x + (((by >> 6) * 256 * 64 + (by & 63)) * 64 + xw);
  unsigned short* oh = XH + (by * 64 + xw) * 256;
#pragma unroll
  for (int j8 = 0; j8 < 8; ++j8) {
    const int c0 = cq * 64 + j8 * 8;
    u32x4 vh;
#pragma unroll
    for (int d = 0; d < 4; ++d) {
      float f0 = xp[(c0 + 2 * d) * 4096];
      float f1 = xp[(c0 + 2 * d + 1) * 4096];
      vh[d] = packbf2(f0, f1);
    }
    *(u32x4*)(oh + c0) = vh;
  }
}

// ---------- weight prep in STAGING ORDER ----------
// AW2[ks][tid(512)][32 elems]: k_gemm's A-stage becomes fully coalesced.
// AF[ks][kc][frag(4)][lane(64)][8 elems]: offc2's fragment loads lane-consecutive.
__global__ void k_wprep_all(const float* __restrict__ wc, const float* __restrict__ wof,
                            unsigned short* __restrict__ AW2,
                            unsigned short* __restrict__ AF) {
  int idx = blockIdx.x * 256 + threadIdx.x;
  if (idx < 589824) {                     // 36*16384
    int ks = idx / 16384;
    int r = idx - ks * 16384;
    int chunk = r >> 5;                   // = consumer tid: ah*256+am
    int e = r & 31;
    int ah = chunk >> 8, am = chunk & 255;
    int col = (ks >> 2) * 256 + (ks & 3) * 64 + ah * 32 + e;
    int c = col & 255, tap = col >> 8;
    AW2[idx] = bfbits(wc[(am * 256 + c) * 9 + tap]);
  } else {
    int j = idx - 589824;
    if (j < 147456) {                     // 72*2048
      int skc = j >> 11;
      int r = j & 2047;
      int fi = r >> 9;                    // 0:hi m, 1:hi m+16, 2:lo m, 3:lo m+16
      int lane = (r >> 3) & 63;
      int e = r & 7;
      int ks = skc >> 1, kc = skc & 1;
      int tap = ks >> 2, q = ks & 3;
      int mr = lane & 15, ko = (lane >> 4) * 8;
      int m = (fi & 1) * 16 + mr;
      int gcol = tap * 256 + q * 64 + ko + kc * 32 + e;
      int c = gcol & 255;
      int t = gcol >> 8;
      float v = (m < 27) ? wof[(m * 256 + c) * 9 + t] : 0.f;
      unsigned short h = bfbits(v);
      AF[j] = (fi >> 1) ? bfbits(v - bf16f(h)) : h;
    }
  }
}

// ---------- offset conv: LDS-staged GEMM, dbuf + prefetch, coalesced A ----------
__global__ __launch_bounds__(256) void k_offc2(const unsigned short* __restrict__ AF,
                                               const unsigned short* __restrict__ XH,
                                               f32x4* __restrict__ W4,
                                               unsigned* __restrict__ C4) {
  __shared__ u32x4 ldsq[1024];   // 16 KB: 2 x 8 KB B-tile dbuf; reused for 8 KB acc
  unsigned char* ldsbase = (unsigned char*)ldsq;
  float* lds32 = (float*)ldsq;

  const int tid = threadIdx.x;
  const int bid = blockIdx.x;            // y(64) x b(8)
  const int b = bid & 7;                 // XCD swizzle: one batch per XCD
  const int y = bid >> 3;
  const int l = tid & 63;
  const int w = tid >> 6;

  const unsigned short* xb = XH + b * (64 * 64 * 256);
  const int sp = tid >> 2;
  const int qtr = tid & 3;
  const unsigned swb = (unsigned)(sp & 7) << 4;
  const int col = w * 16 + (l & 15);
  const unsigned swc = (unsigned)(col & 7) << 4;

  f32x4 acc0 = (f32x4){0.f, 0.f, 0.f, 0.f};
  f32x4 acc1 = (f32x4){0.f, 0.f, 0.f, 0.f};
  u32x4 v0, v1;

  // prologue: stage step 0 into buffer 0
  {
    const int yy = y - 1;
    const int xx = sp - 1;
    const bool valid = ((unsigned)yy < 64u) & ((unsigned)xx < 64u);
    const int yyc = min(max(yy, 0), 63), xxc = min(max(xx, 0), 63);
    const unsigned short* src = xb + ((yyc * 64 + xxc) * 256 + qtr * 16);
    u32x4 z = (u32x4){0u, 0u, 0u, 0u};
    v0 = valid ? *(const u32x4*)src : z;
    v1 = valid ? *(const u32x4*)(src + 8) : z;
    *(u32x4*)(ldsbase + (unsigned)sp * 128u + (((unsigned)(qtr * 32)) ^ swb)) = v0;
    *(u32x4*)(ldsbase + (unsigned)sp * 128u + (((unsigned)(qtr * 32 + 16)) ^ swb)) = v1;
  }

  for (int ks = 0; ks < 36; ++ks) {
    unsigned char* ldsB = ldsbase + (ks & 1) * 8192;
    unsigned char* ldsBn = ldsbase + ((ks & 1) ^ 1) * 8192;
    const bool pf = (ks + 1 < 36);

    // prefetch next stage BEFORE the barrier (stays in flight across it)
    if (pf) {
      int tap = (ks + 1) >> 2, q = (ks + 1) & 3;
      int yy = y + tap / 3 - 1, xx = sp + tap % 3 - 1;
      bool valid = ((unsigned)yy < 64u) & ((unsigned)xx < 64u);
      int yyc = min(max(yy, 0), 63), xxc = min(max(xx, 0), 63);
      const unsigned short* src = xb + ((yyc * 64 + xxc) * 256 + q * 64 + qtr * 16);
      u32x4 z = (u32x4){0u, 0u, 0u, 0u};
      v0 = valid ? *(const u32x4*)src : z;
      v1 = valid ? *(const u32x4*)(src + 8) : z;
    }

    // LDS-only barrier: publish buf[cur] writes, retire buf[cur^1] reads
    asm volatile("s_waitcnt lgkmcnt(0)" ::: "memory");
    __builtin_amdgcn_s_barrier();

    const unsigned short* af = AF + ks * 4096;
#pragma unroll
    for (int kc = 0; kc < 2; ++kc) {
      bf16x8 ah0 = *(const bf16x8*)(af + kc * 2048 + l * 8);
      bf16x8 ah1 = *(const bf16x8*)(af + kc * 2048 + 512 + l * 8);
      bf16x8 al0 = *(const bf16x8*)(af + kc * 2048 + 1024 + l * 8);
      bf16x8 al1 = *(const bf16x8*)(af + kc * 2048 + 1536 + l * 8);
      bf16x8 bh = *(const bf16x8*)(ldsB + (unsigned)col * 128u +
                                   (((unsigned)(kc * 64 + (l >> 4) * 16)) ^ swc));
      acc0 = __builtin_amdgcn_mfma_f32_16x16x32_bf16(ah0, bh, acc0, 0, 0, 0);
      acc1 = __builtin_amdgcn_mfma_f32_16x16x32_bf16(ah1, bh, acc1, 0, 0, 0);
      acc0 = __builtin_amdgcn_mfma_f32_16x16x32_bf16(al0, bh, acc0, 0, 0, 0);
      acc1 = __builtin_amdgcn_mfma_f32_16x16x32_bf16(al1, bh, acc1, 0, 0, 0);
    }

    // write next stage into the other buffer (read side untouched)
    if (pf) {
      *(u32x4*)(ldsBn + (unsigned)sp * 128u + (((unsigned)(qtr * 32)) ^ swb)) = v0;
      *(u32x4*)(ldsBn + (unsigned)sp * 128u + (((unsigned)(qtr * 32 + 16)) ^ swb)) = v1;
    }
  }

  // stage acc -> lds32 [32 m][64 px]  (D layout: col=lane&15, row=(l>>4)*4+reg)
  __syncthreads();
#pragma unroll
  for (int mf = 0; mf < 2; ++mf) {
    f32x4 a = mf ? acc1 : acc0;
#pragma unroll
    for (int r = 0; r < 4; ++r) {
      int m = mf * 16 + (l >> 4) * 4 + r;
      int px = w * 16 + (l & 15);
      lds32[m * 64 + px] = a[r];
    }
  }
  __syncthreads();

  // fused xform: per (k, px) compute bilinear weights + packed corner indices
#pragma unroll
  for (int it = 0; it < 3; ++it) {
    int idx = tid + it * 256;
    if (idx < 9 * 64) {
      int k = idx >> 6, px = idx & 63;
      float oy = lds32[k * 64 + px];
      float ox = lds32[(9 + k) * 64 + px];
      float lg = lds32[(18 + k) * 64 + px];
      int s = y * 64 + px;
      float py = oy + (float)y - 1.f + (float)(k / 3);
      float pxf = ox + (float)px - 1.f + (float)(k % 3);
      float mk = 1.f / (1.f + __expf(-lg));

      float y0f = floorf(py), x0f = floorf(pxf);
      float ly = py - y0f, lx = pxf - x0f;
      int y0 = (int)y0f, x0 = (int)x0f;
      int y1 = y0 + 1, x1 = x0 + 1;
      float omy = 1.f - ly, omx = 1.f - lx;
      bool y0v = (unsigned)y0 < 64u, y1v = (unsigned)y1 < 64u;
      bool x0v = (unsigned)x0 < 64u, x1v = (unsigned)x1 < 64u;
      f32x4 wv;
      wv[0] = (y0v && x0v) ? omy * omx * mk : 0.f;
      wv[1] = (y0v && x1v) ? omy * lx * mk : 0.f;
      wv[2] = (y1v && x0v) ? ly * omx * mk : 0.f;
      wv[3] = (y1v && x1v) ? ly * lx * mk : 0.f;
      int y0c = min(max(y0, 0), 63), y1c = min(max(y1, 0), 63);
      int x0c = min(max(x0, 0), 63), x1c = min(max(x1, 0), 63);
      unsigned p00 = (unsigned)(y0c * 64 + x0c);
      unsigned p11 = (unsigned)(y1c * 64 + x1c);
      int ci = (b * 9 + k) * NSP + s;
      W4[ci] = wv;
      C4[ci] = p00 | (p11 << 16);
    }
  }
}

// ---------- fused sampling + implicit GEMM (dbuf + phase-split schedule) ----------
struct Bld16 {
  u32x4 g00a, g00b, g01a, g01b, g10a, g10b, g11a, g11b;
  f32x4 wv;
};

static __device__ __forceinline__ void loadB16(const unsigned short* __restrict__ xb,
                                               const f32x4* __restrict__ W4,
                                               const unsigned* __restrict__ C4,
                                               int b, int k, int c0, int bc, int s,
                                               Bld16& r) {
  int ci = (b * 9 + k) * NSP + s;
  r.wv = W4[ci];
  unsigned c4 = C4[ci];
  unsigned p00 = c4 & 0xffffu, p11 = c4 >> 16;
  unsigned p01 = (p00 & ~63u) | (p11 & 63u);
  unsigned p10 = (p11 & ~63u) | (p00 & 63u);
  const unsigned short* base = xb + (c0 + bc);
  const unsigned short* q00 = base + (p00 << 8);
  const unsigned short* q01 = base + (p01 << 8);
  const unsigned short* q10 = base + (p10 << 8);
  const unsigned short* q11 = base + (p11 << 8);
  r.g00a = *(const u32x4*)q00;
  r.g00b = *(const u32x4*)(q00 + 8);
  r.g01a = *(const u32x4*)q01;
  r.g01b = *(const u32x4*)(q01 + 8);
  r.g10a = *(const u32x4*)q10;
  r.g10b = *(const u32x4*)(q10 + 8);
  r.g11a = *(const u32x4*)q11;
  r.g11b = *(const u32x4*)(q11 + 8);
}

static __device__ __forceinline__ void blendB16(const Bld16& r, u32x4& o0, u32x4& o1) {
#pragma unroll
  for (int d = 0; d < 4; ++d) {
    float a0 = r.wv[0] * bflo(r.g00a[d]) + r.wv[1] * bflo(r.g01a[d]) +
               r.wv[2] * bflo(r.g10a[d]) + r.wv[3] * bflo(r.g11a[d]);
    float a1 = r.wv[0] * bfhi(r.g00a[d]) + r.wv[1] * bfhi(r.g01a[d]) +
               r.wv[2] * bfhi(r.g10a[d]) + r.wv[3] * bfhi(r.g11a[d]);
    o0[d] = packbf2(a0, a1);
    float b0 = r.wv[0] * bflo(r.g00b[d]) + r.wv[1] * bflo(r.g01b[d]) +
               r.wv[2] * bflo(r.g10b[d]) + r.wv[3] * bflo(r.g11b[d]);
    float b1 = r.wv[0] * bfhi(r.g00b[d]) + r.wv[1] * bfhi(r.g01b[d]) +
               r.wv[2] * bfhi(r.g10b[d]) + r.wv[3] * bfhi(r.g11b[d]);
    o1[d] = packbf2(b0, b1);
  }
}

__global__ __launch_bounds__(512) void k_gemm(const unsigned short* __restrict__ AW2,
                                              const unsigned short* __restrict__ XH,
                                              const f32x4* __restrict__ W4,
                                              const unsigned* __restrict__ C4,
                                              float* __restrict__ out) {
  // double buffer: per buffer 48 KB = A [256][64 bf16] (32 KB) + B [128][64 bf16] (16 KB)
  __shared__ u32x4 lds2[2][3072];
  unsigned char* ldsbase = (unsigned char*)lds2;

  const int tid = threadIdx.x;
  const int bid = blockIdx.x;
  const int b = bid & 7;          // XCD swizzle: one batch per XCD
  const int s0 = (bid >> 3) * 128;

  const int l = tid & 63;
  const int w = tid >> 6;
  const int wm = (w >> 1) * 64;  // 4 M-waves
  const int wn = (w & 1) * 64;   // 2 N-waves

  const int am = tid & 255;
  const int ah = tid >> 8;
  const unsigned swa = (unsigned)(am & 7) << 4;

  const int bn = tid >> 2;
  const int bc = (tid & 3) * 16;
  const int s = s0 + bn;
  const unsigned swb = (unsigned)(bn & 7) << 4;
  const unsigned short* xb = XH + b * (64 * 64 * 256);

  f32x4 acc[4][4];
#pragma unroll
  for (int i = 0; i < 4; ++i)
#pragma unroll
    for (int j = 0; j < 4; ++j) acc[i][j] = (f32x4){0.f, 0.f, 0.f, 0.f};

  u32x4 ar[4];
  u32x4 o0, o1;
  Bld16 bld;

  // prologue: tile 0 -> regs -> buffer 0 (A-stage now coalesced via AW2)
#pragma unroll
  for (int j = 0; j < 4; ++j)
    ar[j] = *(const u32x4*)(AW2 + tid * 32 + j * 8);
  loadB16(xb, W4, C4, b, 0, 0, bc, s, bld);
  blendB16(bld, o0, o1);
  {
    unsigned char* ldsA = ldsbase;
    unsigned char* ldsB = ldsbase + 32768;
    const unsigned abase = (unsigned)am * 128u;
#pragma unroll
    for (int j = 0; j < 4; ++j)
      *(u32x4*)(ldsA + abase + (((unsigned)(ah * 64 + j * 16)) ^ swa)) = ar[j];
    const unsigned bbase = (unsigned)bn * 128u;
    *(u32x4*)(ldsB + bbase + (((unsigned)(bc * 2)) ^ swb)) = o0;
    *(u32x4*)(ldsB + bbase + (((unsigned)(bc * 2 + 16)) ^ swb)) = o1;
  }

  for (int ks = 0; ks < 36; ++ks) {
    const int cur = ks & 1;
    unsigned char* ldsA = ldsbase + cur * 49152;
    unsigned char* ldsB = ldsA + 32768;
    unsigned char* ldsAn = ldsbase + (cur ^ 1) * 49152;
    unsigned char* ldsBn = ldsAn + 32768;

    // LDS-only barrier (no vmcnt drain): publish buf[cur], retire buf[cur^1] reads
    asm volatile("s_waitcnt lgkmcnt(0)" ::: "memory");
    __builtin_amdgcn_s_barrier();

    const int kn = (ks + 1) >> 2, cn = ((ks + 1) & 3) << 6;

    // phase A: issue next tile's A-loads (coalesced; latency hides under MFMA kk=0)
    if (ks + 1 < 36) {
#pragma unroll
      for (int j = 0; j < 4; ++j)
        ar[j] = *(const u32x4*)(AW2 + (ks + 1) * 16384 + tid * 32 + j * 8);
    }

    // MFMA half 1 (kk=0)
    __builtin_amdgcn_s_setprio(1);
    {
      bf16x8 af[4], bfr[4];
      const unsigned co = (unsigned)((l >> 4) * 16);
#pragma unroll
      for (int i = 0; i < 4; ++i) {
        int row = wm + i * 16 + (l & 15);
        af[i] = *(const bf16x8*)(ldsA + (unsigned)row * 128u +
                                 (co ^ ((unsigned)(row & 7) << 4)));
      }
#pragma unroll
      for (int j = 0; j < 4; ++j) {
        int col = wn + j * 16 + (l & 15);
        bfr[j] = *(const bf16x8*)(ldsB + (unsigned)col * 128u +
                                  (co ^ ((unsigned)(col & 7) << 4)));
      }
#pragma unroll
      for (int i = 0; i < 4; ++i)
#pragma unroll
        for (int j = 0; j < 4; ++j)
          acc[i][j] = __builtin_amdgcn_mfma_f32_16x16x32_bf16(af[i], bfr[j],
                                                              acc[i][j], 0, 0, 0);
    }
    __builtin_amdgcn_s_setprio(0);

    // phase B: issue next tile's gathers (latency hides under MFMA kk=1)
    if (ks + 1 < 36) loadB16(xb, W4, C4, b, kn, cn, bc, s, bld);

    // MFMA half 2 (kk=1)
    __builtin_amdgcn_s_setprio(1);
    {
      bf16x8 af[4], bfr[4];
      const unsigned co = (unsigned)(64 + (l >> 4) * 16);
#pragma unroll
      for (int i = 0; i < 4; ++i) {
        int row = wm + i * 16 + (l & 15);
        af[i] = *(const bf16x8*)(ldsA + (unsigned)row * 128u +
                                 (co ^ ((unsigned)(row & 7) << 4)));
      }
#pragma unroll
      for (int j = 0; j < 4; ++j) {
        int col = wn + j * 16 + (l & 15);
        bfr[j] = *(const bf16x8*)(ldsB + (unsigned)col * 128u +
                                  (co ^ ((unsigned)(col & 7) << 4)));
      }
#pragma unroll
      for (int i = 0; i < 4; ++i)
#pragma unroll
        for (int j = 0; j < 4; ++j)
          acc[i][j] = __builtin_amdgcn_mfma_f32_16x16x32_bf16(af[i], bfr[j],
                                                              acc[i][j], 0, 0, 0);
    }
    __builtin_amdgcn_s_setprio(0);

    // phase C: blend + stage next tile into the other buffer
    if (ks + 1 < 36) {
      blendB16(bld, o0, o1);
      const unsigned abase = (unsigned)am * 128u;
#pragma unroll
      for (int j = 0; j < 4; ++j)
        *(u32x4*)(ldsAn + abase + (((unsigned)(ah * 64 + j * 16)) ^ swa)) = ar[j];
      const unsigned bbase = (unsigned)bn * 128u;
      *(u32x4*)(ldsBn + bbase + (((unsigned)(bc * 2)) ^ swb)) = o0;
      *(u32x4*)(ldsBn + bbase + (((unsigned)(bc * 2 + 16)) ^ swb)) = o1;
    }
  }

  // epilogue: D layout col=lane&15, row=(lane>>4)*4+reg (m89)
  const int cn2 = l & 15;
  const int r0 = (l >> 4) * 4;
#pragma unroll
  for (int i = 0; i < 4; ++i) {
#pragma unroll
    for (int j = 0; j < 4; ++j) {
      int sc = s0 + wn + j * 16 + cn2;
#pragma unroll
      for (int r = 0; r < 4; ++r) {
        int o = wm + i * 16 + r0 + r;
        out[((b * 256 + o) << 12) + sc] = acc[i][j][r];
      }
    }
  }
}

extern "C" void kernel_launch(void* const* d_in, const int* in_sizes, int n_in,
                              void* d_out, int out_size, void* d_ws, size_t ws_size,
                              hipStream_t stream) {
  const float* x = (const float*)d_in[0];
  const float* wof = (const float*)d_in[1];
  const float* wc = (const float*)d_in[2];
  float* out = (float*)d_out;
  char* ws = (char*)d_ws;

  // ws layout (total 24.2 MB)
  unsigned short* XH = (unsigned short*)(ws);              // 16,777,216 B
  unsigned short* AW2 = (unsigned short*)(ws + 16777216);  //  1,179,648 B
  unsigned short* AF = (unsigned short*)(ws + 17956864);   //    294,912 B
  f32x4* W4 = (f32x4*)(ws + 18251776);                     //  4,718,592 B
  unsigned* C4 = (unsigned*)(ws + 22970368);               //  1,179,648 B (end 24,150,016)

  k_nhwc<<<512, 256, 0, stream>>>(x, XH);
  k_wprep_all<<<2880, 256, 0, stream>>>(wc, wof, AW2, AF);
  k_offc2<<<512, 256, 0, stream>>>(AF, XH, W4, C4);
  k_gemm<<<256, 512, 0, stream>>>(AW2, XH, W4, C4, out);
}

// Round 16
// 121.564 us; speedup vs baseline: 2.1389x; 1.0409x over previous
//
#include <hip/hip_runtime.h>
#include <hip/hip_bf16.h>

typedef float f32x4 __attribute__((ext_vector_type(4)));
typedef unsigned int u32x4 __attribute__((ext_vector_type(4)));
typedef __bf16 bf16x8 __attribute__((ext_vector_type(8)));

#define NSP 4096
#define KTOT 2304

static __device__ __forceinline__ float bflo(unsigned u) {
  return __builtin_bit_cast(float, u << 16);
}
static __device__ __forceinline__ float bfhi(unsigned u) {
  return __builtin_bit_cast(float, u & 0xffff0000u);
}
static __device__ __forceinline__ unsigned short bfbits(float f) {
  return __builtin_bit_cast(unsigned short, (__bf16)f);
}
static __device__ __forceinline__ unsigned packbf2(float f0, float f1) {
  return (unsigned)bfbits(f0) | ((unsigned)bfbits(f1) << 16);
}
static __device__ __forceinline__ float bf16f(unsigned short h) {
  return __builtin_bit_cast(float, (unsigned)h << 16);
}

// ---------- x (B,C,H,W) f32 -> XH (B,H,W,C) bf16 ----------
__global__ __launch_bounds__(256) void k_nhwc(const float* __restrict__ x,
                                              unsigned short* __restrict__ XH) {
  const int by = blockIdx.x;            // b*64 + y
  const int t = threadIdx.x;
  const int xw = t & 63;
  const int cq = t >> 6;                // 0..3
  const float* xp = x + (((by >> 6) * 256 * 64 + (by & 63)) * 64 + xw);
  unsigned short* oh = XH + (by * 64 + xw) * 256;
#pragma unroll
  for (int j8 = 0; j8 < 8; ++j8) {
    const int c0 = cq * 64 + j8 * 8;
    u32x4 vh;
#pragma unroll
    for (int d = 0; d < 4; ++d) {
      float f0 = xp[(c0 + 2 * d) * 4096];
      float f1 = xp[(c0 + 2 * d + 1) * 4096];
      vh[d] = packbf2(f0, f1);
    }
    *(u32x4*)(oh + c0) = vh;
  }
}

// ---------- weight prep in STAGING ORDER ----------
__global__ void k_wprep_all(const float* __restrict__ wc, const float* __restrict__ wof,
                            unsigned short* __restrict__ AW2,
                            unsigned short* __restrict__ AF) {
  int idx = blockIdx.x * 256 + threadIdx.x;
  if (idx < 589824) {                     // 36*16384
    int ks = idx / 16384;
    int r = idx - ks * 16384;
    int chunk = r >> 5;                   // = consumer tid: ah*256+am
    int e = r & 31;
    int ah = chunk >> 8, am = chunk & 255;
    int col = (ks >> 2) * 256 + (ks & 3) * 64 + ah * 32 + e;
    int c = col & 255, tap = col >> 8;
    AW2[idx] = bfbits(wc[(am * 256 + c) * 9 + tap]);
  } else {
    int j = idx - 589824;
    if (j < 147456) {                     // 72*2048
      int skc = j >> 11;
      int r = j & 2047;
      int fi = r >> 9;                    // 0:hi m, 1:hi m+16, 2:lo m, 3:lo m+16
      int lane = (r >> 3) & 63;
      int e = r & 7;
      int ks = skc >> 1, kc = skc & 1;
      int tap = ks >> 2, q = ks & 3;
      int mr = lane & 15, ko = (lane >> 4) * 8;
      int m = (fi & 1) * 16 + mr;
      int gcol = tap * 256 + q * 64 + ko + kc * 32 + e;
      int c = gcol & 255;
      int t = gcol >> 8;
      float v = (m < 27) ? wof[(m * 256 + c) * 9 + t] : 0.f;
      unsigned short h = bfbits(v);
      AF[j] = (fi >> 1) ? bfbits(v - bf16f(h)) : h;
    }
  }
}

// ---------- offset conv: LDS-staged GEMM, dbuf + prefetch, coalesced A ----------
__global__ __launch_bounds__(256) void k_offc2(const unsigned short* __restrict__ AF,
                                               const unsigned short* __restrict__ XH,
                                               f32x4* __restrict__ W4,
                                               unsigned* __restrict__ C4) {
  __shared__ u32x4 ldsq[1024];   // 16 KB: 2 x 8 KB B-tile dbuf; reused for 8 KB acc
  unsigned char* ldsbase = (unsigned char*)ldsq;
  float* lds32 = (float*)ldsq;

  const int tid = threadIdx.x;
  const int bid = blockIdx.x;            // y(64) x b(8)
  const int b = bid & 7;                 // XCD swizzle: one batch per XCD
  const int y = bid >> 3;
  const int l = tid & 63;
  const int w = tid >> 6;

  const unsigned short* xb = XH + b * (64 * 64 * 256);
  const int sp = tid >> 2;
  const int qtr = tid & 3;
  const unsigned swb = (unsigned)(sp & 7) << 4;
  const int col = w * 16 + (l & 15);
  const unsigned swc = (unsigned)(col & 7) << 4;

  f32x4 acc0 = (f32x4){0.f, 0.f, 0.f, 0.f};
  f32x4 acc1 = (f32x4){0.f, 0.f, 0.f, 0.f};
  u32x4 v0, v1;

  // prologue: stage step 0 into buffer 0
  {
    const int yy = y - 1;
    const int xx = sp - 1;
    const bool valid = ((unsigned)yy < 64u) & ((unsigned)xx < 64u);
    const int yyc = min(max(yy, 0), 63), xxc = min(max(xx, 0), 63);
    const unsigned short* src = xb + ((yyc * 64 + xxc) * 256 + qtr * 16);
    u32x4 z = (u32x4){0u, 0u, 0u, 0u};
    v0 = valid ? *(const u32x4*)src : z;
    v1 = valid ? *(const u32x4*)(src + 8) : z;
    *(u32x4*)(ldsbase + (unsigned)sp * 128u + (((unsigned)(qtr * 32)) ^ swb)) = v0;
    *(u32x4*)(ldsbase + (unsigned)sp * 128u + (((unsigned)(qtr * 32 + 16)) ^ swb)) = v1;
  }

  for (int ks = 0; ks < 36; ++ks) {
    unsigned char* ldsB = ldsbase + (ks & 1) * 8192;
    unsigned char* ldsBn = ldsbase + ((ks & 1) ^ 1) * 8192;
    const bool pf = (ks + 1 < 36);

    // prefetch next stage BEFORE the barrier (stays in flight across it)
    if (pf) {
      int tap = (ks + 1) >> 2, q = (ks + 1) & 3;
      int yy = y + tap / 3 - 1, xx = sp + tap % 3 - 1;
      bool valid = ((unsigned)yy < 64u) & ((unsigned)xx < 64u);
      int yyc = min(max(yy, 0), 63), xxc = min(max(xx, 0), 63);
      const unsigned short* src = xb + ((yyc * 64 + xxc) * 256 + q * 64 + qtr * 16);
      u32x4 z = (u32x4){0u, 0u, 0u, 0u};
      v0 = valid ? *(const u32x4*)src : z;
      v1 = valid ? *(const u32x4*)(src + 8) : z;
    }

    // LDS-only barrier: publish buf[cur] writes, retire buf[cur^1] reads
    asm volatile("s_waitcnt lgkmcnt(0)" ::: "memory");
    __builtin_amdgcn_s_barrier();

    const unsigned short* af = AF + ks * 4096;
#pragma unroll
    for (int kc = 0; kc < 2; ++kc) {
      bf16x8 ah0 = *(const bf16x8*)(af + kc * 2048 + l * 8);
      bf16x8 ah1 = *(const bf16x8*)(af + kc * 2048 + 512 + l * 8);
      bf16x8 al0 = *(const bf16x8*)(af + kc * 2048 + 1024 + l * 8);
      bf16x8 al1 = *(const bf16x8*)(af + kc * 2048 + 1536 + l * 8);
      bf16x8 bh = *(const bf16x8*)(ldsB + (unsigned)col * 128u +
                                   (((unsigned)(kc * 64 + (l >> 4) * 16)) ^ swc));
      acc0 = __builtin_amdgcn_mfma_f32_16x16x32_bf16(ah0, bh, acc0, 0, 0, 0);
      acc1 = __builtin_amdgcn_mfma_f32_16x16x32_bf16(ah1, bh, acc1, 0, 0, 0);
      acc0 = __builtin_amdgcn_mfma_f32_16x16x32_bf16(al0, bh, acc0, 0, 0, 0);
      acc1 = __builtin_amdgcn_mfma_f32_16x16x32_bf16(al1, bh, acc1, 0, 0, 0);
    }

    // write next stage into the other buffer (read side untouched)
    if (pf) {
      *(u32x4*)(ldsBn + (unsigned)sp * 128u + (((unsigned)(qtr * 32)) ^ swb)) = v0;
      *(u32x4*)(ldsBn + (unsigned)sp * 128u + (((unsigned)(qtr * 32 + 16)) ^ swb)) = v1;
    }
  }

  // stage acc -> lds32 [32 m][64 px]  (D layout: col=lane&15, row=(l>>4)*4+reg)
  __syncthreads();
#pragma unroll
  for (int mf = 0; mf < 2; ++mf) {
    f32x4 a = mf ? acc1 : acc0;
#pragma unroll
    for (int r = 0; r < 4; ++r) {
      int m = mf * 16 + (l >> 4) * 4 + r;
      int px = w * 16 + (l & 15);
      lds32[m * 64 + px] = a[r];
    }
  }
  __syncthreads();

  // fused xform: per (k, px) compute bilinear weights + packed corner indices
#pragma unroll
  for (int it = 0; it < 3; ++it) {
    int idx = tid + it * 256;
    if (idx < 9 * 64) {
      int k = idx >> 6, px = idx & 63;
      float oy = lds32[k * 64 + px];
      float ox = lds32[(9 + k) * 64 + px];
      float lg = lds32[(18 + k) * 64 + px];
      int s = y * 64 + px;
      float py = oy + (float)y - 1.f + (float)(k / 3);
      float pxf = ox + (float)px - 1.f + (float)(k % 3);
      float mk = 1.f / (1.f + __expf(-lg));

      float y0f = floorf(py), x0f = floorf(pxf);
      float ly = py - y0f, lx = pxf - x0f;
      int y0 = (int)y0f, x0 = (int)x0f;
      int y1 = y0 + 1, x1 = x0 + 1;
      float omy = 1.f - ly, omx = 1.f - lx;
      bool y0v = (unsigned)y0 < 64u, y1v = (unsigned)y1 < 64u;
      bool x0v = (unsigned)x0 < 64u, x1v = (unsigned)x1 < 64u;
      f32x4 wv;
      wv[0] = (y0v && x0v) ? omy * omx * mk : 0.f;
      wv[1] = (y0v && x1v) ? omy * lx * mk : 0.f;
      wv[2] = (y1v && x0v) ? ly * omx * mk : 0.f;
      wv[3] = (y1v && x1v) ? ly * lx * mk : 0.f;
      int y0c = min(max(y0, 0), 63), y1c = min(max(y1, 0), 63);
      int x0c = min(max(x0, 0), 63), x1c = min(max(x1, 0), 63);
      unsigned p00 = (unsigned)(y0c * 64 + x0c);
      unsigned p11 = (unsigned)(y1c * 64 + x1c);
      int ci = (b * 9 + k) * NSP + s;
      W4[ci] = wv;
      C4[ci] = p00 | (p11 << 16);
    }
  }
}

// ---------- fused sampling + implicit GEMM (2-deep pipelined schedule) ----------
struct Bld16 {
  u32x4 g00a, g00b, g01a, g01b, g10a, g10b, g11a, g11b;
  f32x4 wv;
};

static __device__ __forceinline__ void loadMeta(const f32x4* __restrict__ W4,
                                                const unsigned* __restrict__ C4,
                                                int b, int k, int s,
                                                f32x4& wv, unsigned& c4) {
  int ci = (b * 9 + k) * NSP + s;
  wv = W4[ci];
  c4 = C4[ci];
}

static __device__ __forceinline__ void loadCorners(const unsigned short* __restrict__ xb,
                                                   f32x4 wv, unsigned c4, int c0, int bc,
                                                   Bld16& r) {
  r.wv = wv;
  unsigned p00 = c4 & 0xffffu, p11 = c4 >> 16;
  unsigned p01 = (p00 & ~63u) | (p11 & 63u);
  unsigned p10 = (p11 & ~63u) | (p00 & 63u);
  const unsigned short* base = xb + (c0 + bc);
  const unsigned short* q00 = base + (p00 << 8);
  const unsigned short* q01 = base + (p01 << 8);
  const unsigned short* q10 = base + (p10 << 8);
  const unsigned short* q11 = base + (p11 << 8);
  r.g00a = *(const u32x4*)q00;
  r.g00b = *(const u32x4*)(q00 + 8);
  r.g01a = *(const u32x4*)q01;
  r.g01b = *(const u32x4*)(q01 + 8);
  r.g10a = *(const u32x4*)q10;
  r.g10b = *(const u32x4*)(q10 + 8);
  r.g11a = *(const u32x4*)q11;
  r.g11b = *(const u32x4*)(q11 + 8);
}

static __device__ __forceinline__ void blendB16(const Bld16& r, u32x4& o0, u32x4& o1) {
#pragma unroll
  for (int d = 0; d < 4; ++d) {
    float a0 = r.wv[0] * bflo(r.g00a[d]) + r.wv[1] * bflo(r.g01a[d]) +
               r.wv[2] * bflo(r.g10a[d]) + r.wv[3] * bflo(r.g11a[d]);
    float a1 = r.wv[0] * bfhi(r.g00a[d]) + r.wv[1] * bfhi(r.g01a[d]) +
               r.wv[2] * bfhi(r.g10a[d]) + r.wv[3] * bfhi(r.g11a[d]);
    o0[d] = packbf2(a0, a1);
    float b0 = r.wv[0] * bflo(r.g00b[d]) + r.wv[1] * bflo(r.g01b[d]) +
               r.wv[2] * bflo(r.g10b[d]) + r.wv[3] * bflo(r.g11b[d]);
    float b1 = r.wv[0] * bfhi(r.g00b[d]) + r.wv[1] * bfhi(r.g01b[d]) +
               r.wv[2] * bfhi(r.g10b[d]) + r.wv[3] * bfhi(r.g11b[d]);
    o1[d] = packbf2(b0, b1);
  }
}

__global__ __launch_bounds__(512) void k_gemm(const unsigned short* __restrict__ AW2,
                                              const unsigned short* __restrict__ XH,
                                              const f32x4* __restrict__ W4,
                                              const unsigned* __restrict__ C4v,
                                              float* __restrict__ out) {
  // double buffer: per buffer 48 KB = A [256][64 bf16] (32 KB) + B [128][64 bf16] (16 KB)
  __shared__ u32x4 lds2[2][3072];
  unsigned char* ldsbase = (unsigned char*)lds2;

  const int tid = threadIdx.x;
  const int bid = blockIdx.x;
  const int b = bid & 7;          // XCD swizzle: one batch per XCD
  const int s0 = (bid >> 3) * 128;

  const int l = tid & 63;
  const int w = tid >> 6;
  const int wm = (w >> 1) * 64;  // 4 M-waves
  const int wn = (w & 1) * 64;   // 2 N-waves

  const int am = tid & 255;
  const int ah = tid >> 8;
  const unsigned swa = (unsigned)(am & 7) << 4;

  const int bn = tid >> 2;
  const int bc = (tid & 3) * 16;
  const int s = s0 + bn;
  const unsigned swb = (unsigned)(bn & 7) << 4;
  const unsigned short* xb = XH + b * (64 * 64 * 256);

  f32x4 acc[4][4];
#pragma unroll
  for (int i = 0; i < 4; ++i)
#pragma unroll
    for (int j = 0; j < 4; ++j) acc[i][j] = (f32x4){0.f, 0.f, 0.f, 0.f};

  // 2-deep pipeline register sets (named, statically indexed — rule #20)
  f32x4 mwvA, mwvB;
  unsigned mc4A, mc4B;
  Bld16 bldA, bldB;
  u32x4 arA[4], arB[4];

  // ---- prologue ----
  loadMeta(W4, C4v, b, 0, s, mwvA, mc4A);   // meta(0)
  loadMeta(W4, C4v, b, 0, s, mwvB, mc4B);   // meta(1)
#pragma unroll
  for (int j = 0; j < 4; ++j) arA[j] = *(const u32x4*)(AW2 + tid * 32 + j * 8);
  loadCorners(xb, mwvA, mc4A, 0, bc, bldA);              // corners(0)
  loadMeta(W4, C4v, b, 0, s, mwvA, mc4A);   // meta(2)
  {
    u32x4 o0, o1;
    blendB16(bldA, o0, o1);
    unsigned char* ldsA = ldsbase;
    unsigned char* ldsB = ldsbase + 32768;
    const unsigned abase = (unsigned)am * 128u;
#pragma unroll
    for (int j = 0; j < 4; ++j)
      *(u32x4*)(ldsA + abase + (((unsigned)(ah * 64 + j * 16)) ^ swa)) = arA[j];
    const unsigned bbase = (unsigned)bn * 128u;
    *(u32x4*)(ldsB + bbase + (((unsigned)(bc * 2)) ^ swb)) = o0;
    *(u32x4*)(ldsB + bbase + (((unsigned)(bc * 2 + 16)) ^ swb)) = o1;
  }
#pragma unroll
  for (int j = 0; j < 4; ++j)
    arB[j] = *(const u32x4*)(AW2 + 16384 + tid * 32 + j * 8);   // A(1)
  loadCorners(xb, mwvB, mc4B, 64, bc, bldB);             // corners(1)

  // one pipelined step; issue sets (I) get step KS+2/meta KS+3, use sets (U) hold KS+1
  auto mfma_half = [&](unsigned char* ldsA, unsigned char* ldsB, int H) {
    bf16x8 af[4], bfr[4];
    const unsigned co = (unsigned)(H * 64 + ((l >> 4) * 16));
#pragma unroll
    for (int i = 0; i < 4; ++i) {
      int row = wm + i * 16 + (l & 15);
      af[i] = *(const bf16x8*)(ldsA + (unsigned)row * 128u +
                               (co ^ ((unsigned)(row & 7) << 4)));
    }
#pragma unroll
    for (int j = 0; j < 4; ++j) {
      int col = wn + j * 16 + (l & 15);
      bfr[j] = *(const bf16x8*)(ldsB + (unsigned)col * 128u +
                                (co ^ ((unsigned)(col & 7) << 4)));
    }
#pragma unroll
    for (int i = 0; i < 4; ++i)
#pragma unroll
      for (int j = 0; j < 4; ++j)
        acc[i][j] = __builtin_amdgcn_mfma_f32_16x16x32_bf16(af[i], bfr[j],
                                                            acc[i][j], 0, 0, 0);
  };

  auto gstep = [&](int KS, u32x4 (&arI)[4], Bld16& bldI, f32x4& mwvI, unsigned& mc4I,
                   f32x4& mwvO, unsigned& mc4O, u32x4 (&arU)[4], Bld16& bldU) {
    const int cur = KS & 1;
    unsigned char* ldsA = ldsbase + cur * 49152;
    unsigned char* ldsB = ldsA + 32768;
    unsigned char* ldsAn = ldsbase + (cur ^ 1) * 49152;
    unsigned char* ldsBn = ldsAn + 32768;

    // issue A(KS+2) — coalesced, flies for ~2 steps
    if (KS + 2 < 36) {
#pragma unroll
      for (int j = 0; j < 4; ++j)
        arI[j] = *(const u32x4*)(AW2 + (KS + 2) * 16384 + tid * 32 + j * 8);
    }

    // LDS-only barrier (no vmcnt drain): publish buf[cur], retire buf[cur^1] reads
    asm volatile("s_waitcnt lgkmcnt(0)" ::: "memory");
    __builtin_amdgcn_s_barrier();

    __builtin_amdgcn_s_setprio(1);
    mfma_half(ldsA, ldsB, 0);
    __builtin_amdgcn_s_setprio(0);

    // issue corners(KS+2) — addresses from meta loaded a full step ago
    if (KS + 2 < 36)
      loadCorners(xb, mwvI, mc4I, ((KS + 2) & 3) << 6, bc, bldI);
    // issue meta(KS+3) into the freed opposite meta set
    if (KS + 3 < 36)
      loadMeta(W4, C4v, b, (KS + 3) >> 2, s, mwvO, mc4O);

    __builtin_amdgcn_s_setprio(1);
    mfma_half(ldsA, ldsB, 1);
    __builtin_amdgcn_s_setprio(0);

    // blend + stage tile KS+1 (its loads have flown ~1.5 steps; counted vmcnt)
    if (KS + 1 < 36) {
      u32x4 o0, o1;
      blendB16(bldU, o0, o1);
      const unsigned abase = (unsigned)am * 128u;
#pragma unroll
      for (int j = 0; j < 4; ++j)
        *(u32x4*)(ldsAn + abase + (((unsigned)(ah * 64 + j * 16)) ^ swa)) = arU[j];
      const unsigned bbase = (unsigned)bn * 128u;
      *(u32x4*)(ldsBn + bbase + (((unsigned)(bc * 2)) ^ swb)) = o0;
      *(u32x4*)(ldsBn + bbase + (((unsigned)(bc * 2 + 16)) ^ swb)) = o1;
    }
  };

  for (int ks2 = 0; ks2 < 36; ks2 += 2) {
    gstep(ks2, arA, bldA, mwvA, mc4A, mwvB, mc4B, arB, bldB);
    gstep(ks2 + 1, arB, bldB, mwvB, mc4B, mwvA, mc4A, arA, bldA);
  }

  // epilogue: D layout col=lane&15, row=(lane>>4)*4+reg (m89)
  const int cn2 = l & 15;
  const int r0 = (l >> 4) * 4;
#pragma unroll
  for (int i = 0; i < 4; ++i) {
#pragma unroll
    for (int j = 0; j < 4; ++j) {
      int sc = s0 + wn + j * 16 + cn2;
#pragma unroll
      for (int r = 0; r < 4; ++r) {
        int o = wm + i * 16 + r0 + r;
        out[((b * 256 + o) << 12) + sc] = acc[i][j][r];
      }
    }
  }
}

extern "C" void kernel_launch(void* const* d_in, const int* in_sizes, int n_in,
                              void* d_out, int out_size, void* d_ws, size_t ws_size,
                              hipStream_t stream) {
  const float* x = (const float*)d_in[0];
  const float* wof = (const float*)d_in[1];
  const float* wc = (const float*)d_in[2];
  float* out = (float*)d_out;
  char* ws = (char*)d_ws;

  // ws layout (total 24.2 MB)
  unsigned short* XH = (unsigned short*)(ws);              // 16,777,216 B
  unsigned short* AW2 = (unsigned short*)(ws + 16777216);  //  1,179,648 B
  unsigned short* AF = (unsigned short*)(ws + 17956864);   //    294,912 B
  f32x4* W4 = (f32x4*)(ws + 18251776);                     //  4,718,592 B
  unsigned* C4 = (unsigned*)(ws + 22970368);               //  1,179,648 B (end 24,150,016)

  k_nhwc<<<512, 256, 0, stream>>>(x, XH);
  k_wprep_all<<<2880, 256, 0, stream>>>(wc, wof, AW2, AF);
  k_offc2<<<512, 256, 0, stream>>>(AF, XH, W4, C4);
  k_gemm<<<256, 512, 0, stream>>>(AW2, XH, W4, C4, out);
}